// Round 3
// baseline (4675.987 us; speedup 1.0000x reference)
//
#include <hip/hip_runtime.h>
#include <math.h>

#define NN 100000
#define NE 1600000
#define D 64
#define NL 3
#define NG 2000
#define LN_EPS 1e-5f

// ---------------- scatter-add: agg[dst] += xin[src] ----------------
// 16 threads per edge, 4 features each (float4 gather, 4 fp32 atomics)
__global__ __launch_bounds__(256) void k_scatter(const int* __restrict__ src,
                                                 const int* __restrict__ dst,
                                                 const float* __restrict__ xin,
                                                 float* __restrict__ agg) {
    int t = blockIdx.x * 256 + threadIdx.x;
    int e = t >> 4;
    int fg = (t & 15) * 4;
    int s = src[e], d = dst[e];
    const float4 v = *(const float4*)(xin + (long)s * D + fg);
    float* a = agg + (long)d * D + fg;
    unsafeAtomicAdd(a + 0, v.x);
    unsafeAtomicAdd(a + 1, v.y);
    unsafeAtomicAdd(a + 2, v.z);
    unsafeAtomicAdd(a + 3, v.w);
}

// ---------------- fused GIN update + MLP + LayerNorm ----------------
// block = 256 = 4 waves; one wave per node; lane = feature
__global__ __launch_bounds__(256) void k_mlp(const float* __restrict__ xin,
                                             const float* __restrict__ agg,
                                             float* __restrict__ xout,
                                             const float* __restrict__ W1,
                                             const float* __restrict__ b1,
                                             const float* __restrict__ W2,
                                             const float* __restrict__ b2,
                                             const float* __restrict__ epsp,
                                             const float* __restrict__ lng,
                                             const float* __restrict__ lnb) {
    __shared__ float sh[4][D];
    int w = threadIdx.x >> 6;
    int lane = threadIdx.x & 63;
    int node = blockIdx.x * 4 + w;
    long base = (long)node * D;

    float epsv = 1.0f + *epsp;
    float h = epsv * xin[base + lane] + agg[base + lane];
    sh[w][lane] = h;
    __syncthreads();

    // y1 = silu(h @ W1 + b1)
    float a1 = b1[lane];
#pragma unroll
    for (int k = 0; k < D; k++) a1 += sh[w][k] * W1[k * D + lane];
    a1 = a1 / (1.0f + __expf(-a1));

    __syncthreads();
    sh[w][lane] = a1;
    __syncthreads();

    // y2 = y1 @ W2 + b2
    float a2 = b2[lane];
#pragma unroll
    for (int k = 0; k < D; k++) a2 += sh[w][k] * W2[k * D + lane];

    // LayerNorm over 64 lanes
    float s = a2;
#pragma unroll
    for (int m = 32; m >= 1; m >>= 1) s += __shfl_xor(s, m, 64);
    float mu = s * (1.0f / 64.0f);
    float dd = a2 - mu;
    float v = dd * dd;
#pragma unroll
    for (int m = 32; m >= 1; m >>= 1) v += __shfl_xor(v, m, 64);
    float inv = rsqrtf(v * (1.0f / 64.0f) + LN_EPS);
    xout[base + lane] = dd * inv * lng[lane] + lnb[lane];
}

// ---------------- gate MLP: gate[n] = gw2 . silu(x gw1 + gb1) + gb2 ----------------
__global__ __launch_bounds__(256) void k_gate(const float* __restrict__ xf,
                                              const float* __restrict__ gw1,
                                              const float* __restrict__ gb1,
                                              const float* __restrict__ gw2,
                                              const float* __restrict__ gb2,
                                              float* __restrict__ gate) {
    __shared__ float sh[4][D];
    int w = threadIdx.x >> 6;
    int lane = threadIdx.x & 63;
    int node = blockIdx.x * 4 + w;
    sh[w][lane] = xf[(long)node * D + lane];
    __syncthreads();

    float c = 0.0f;
    if (lane < 32) {
        float a = gb1[lane];
#pragma unroll
        for (int k = 0; k < D; k++) a += sh[w][k] * gw1[k * 32 + lane];
        a = a / (1.0f + __expf(-a));
        c = a * gw2[lane];
    }
#pragma unroll
    for (int m = 32; m >= 1; m >>= 1) c += __shfl_xor(c, m, 64);
    if (lane == 0) gate[node] = c + gb2[0];
}

// ---------------- per-graph softmax pooling ----------------
// one block (64 threads) per graph; batch is sorted -> binary search range
__global__ __launch_bounds__(64) void k_pool(const float* __restrict__ xf,
                                             const float* __restrict__ gate,
                                             const int* __restrict__ batch,
                                             float* __restrict__ out) {
    int g = blockIdx.x;
    int lane = threadIdx.x;

    int lo = 0, hi = NN;
    while (lo < hi) { int mid = (lo + hi) >> 1; if (batch[mid] < g) lo = mid + 1; else hi = mid; }
    int start = lo;
    hi = NN;
    while (lo < hi) { int mid = (lo + hi) >> 1; if (batch[mid] < g + 1) lo = mid + 1; else hi = mid; }
    int end = lo;

    if (start >= end) { out[(long)g * D + lane] = 0.0f; return; }

    // per-graph max
    float m = -INFINITY;
    for (int n = start + lane; n < end; n += 64) m = fmaxf(m, gate[n]);
#pragma unroll
    for (int mm = 32; mm >= 1; mm >>= 1) m = fmaxf(m, __shfl_xor(m, mm, 64));

    // softmax denom
    float s = 0.0f;
    for (int n = start + lane; n < end; n += 64) s += __expf(gate[n] - m);
#pragma unroll
    for (int mm = 32; mm >= 1; mm >>= 1) s += __shfl_xor(s, mm, 64);

    // weighted feature sum (lane = feature)
    float acc = 0.0f;
    for (int n = start; n < end; n++) acc += __expf(gate[n] - m) * xf[(long)n * D + lane];

    out[(long)g * D + lane] = acc / s;
}

extern "C" void kernel_launch(void* const* d_in, const int* in_sizes, int n_in,
                              void* d_out, int out_size, void* d_ws, size_t ws_size,
                              hipStream_t stream) {
    const float* x   = (const float*)d_in[0];
    const int* ei    = (const int*)d_in[1];
    const int* batch = (const int*)d_in[2];
    const float* W1  = (const float*)d_in[3];
    const float* b1  = (const float*)d_in[4];
    const float* W2  = (const float*)d_in[5];
    const float* b2  = (const float*)d_in[6];
    const float* eps = (const float*)d_in[7];
    const float* lng = (const float*)d_in[8];
    const float* lnb = (const float*)d_in[9];
    const float* gw1 = (const float*)d_in[10];
    const float* gb1 = (const float*)d_in[11];
    const float* gw2 = (const float*)d_in[12];
    const float* gb2 = (const float*)d_in[13];

    const int* src = ei;
    const int* dst = ei + NE;

    float* xf   = (float*)d_ws;            // NN*D floats (updated features)
    float* agg  = xf + (long)NN * D;       // NN*D floats
    float* gate = agg + (long)NN * D;      // NN floats

    float* out = (float*)d_out;            // fp32 output [G, D]

    for (int l = 0; l < NL; l++) {
        const float* xin = (l == 0) ? x : xf;
        hipMemsetAsync(agg, 0, (size_t)NN * D * sizeof(float), stream);
        k_scatter<<<(NE * 16) / 256, 256, 0, stream>>>(src, dst, xin, agg);
        k_mlp<<<NN / 4, 256, 0, stream>>>(xin, agg, xf,
                                          W1 + (long)l * D * D, b1 + (long)l * D,
                                          W2 + (long)l * D * D, b2 + (long)l * D,
                                          eps + l, lng + (long)l * D, lnb + (long)l * D);
    }

    k_gate<<<NN / 4, 256, 0, stream>>>(xf, gw1, gb1, gw2, gb2, gate);
    k_pool<<<NG, 64, 0, stream>>>(xf, gate, batch, out);
}

// Round 4
// 1268.654 us; speedup vs baseline: 3.6858x; 3.6858x over previous
//
#include <hip/hip_runtime.h>
#include <math.h>

#define NN 100000
#define NE 1600000
#define D 64
#define NL 3
#define NG 2000
#define LN_EPS 1e-5f
#define SCAN_T 1024
#define CHUNK ((NN + SCAN_T - 1) / SCAN_T)   // 98

// ---------------- CSR build: histogram of dst ----------------
__global__ __launch_bounds__(256) void k_hist(const int* __restrict__ dst,
                                              int* __restrict__ counts) {
    int e = blockIdx.x * 256 + threadIdx.x;
    atomicAdd(&counts[dst[e]], 1);
}

// ---------------- CSR build: exclusive scan (single block) ----------------
__global__ __launch_bounds__(SCAN_T) void k_scan(const int* __restrict__ counts,
                                                 int* __restrict__ row_ptr) {
    __shared__ int ssum[SCAN_T];
    int tid = threadIdx.x;
    int beg = tid * CHUNK;
    int end = min(beg + CHUNK, NN);
    int s = 0;
    for (int i = beg; i < end; i++) s += counts[i];
    ssum[tid] = s;
    __syncthreads();
    // inclusive Hillis-Steele scan
    for (int off = 1; off < SCAN_T; off <<= 1) {
        int v = (tid >= off) ? ssum[tid - off] : 0;
        __syncthreads();
        ssum[tid] += v;
        __syncthreads();
    }
    int run = ssum[tid] - s;  // exclusive base for this chunk
    for (int i = beg; i < end; i++) { row_ptr[i] = run; run += counts[i]; }
    if (tid == SCAN_T - 1) row_ptr[NN] = ssum[SCAN_T - 1];
}

// ---------------- CSR build: fill col with src per dst-slot ----------------
__global__ __launch_bounds__(256) void k_fill(const int* __restrict__ src,
                                              const int* __restrict__ dst,
                                              int* __restrict__ cursor,
                                              int* __restrict__ col) {
    int e = blockIdx.x * 256 + threadIdx.x;
    int pos = atomicAdd(&cursor[dst[e]], 1);
    col[pos] = src[e];
}

// ---------------- fused gather + GIN update + MLP + LayerNorm ----------------
// block = 256 = 4 waves; one wave per node; lane = feature
__global__ __launch_bounds__(256) void k_fused(const float* __restrict__ xin,
                                               float* __restrict__ xout,
                                               const int* __restrict__ row_ptr,
                                               const int* __restrict__ col,
                                               const float* __restrict__ W1,
                                               const float* __restrict__ b1,
                                               const float* __restrict__ W2,
                                               const float* __restrict__ b2,
                                               const float* __restrict__ epsp,
                                               const float* __restrict__ lng,
                                               const float* __restrict__ lnb) {
    __shared__ float sh[4][D];
    int w = threadIdx.x >> 6;
    int lane = threadIdx.x & 63;
    int node = blockIdx.x * 4 + w;
    long base = (long)node * D;

    // gather: agg = sum over incoming edges of xin[src]
    int start = row_ptr[node];
    int end   = row_ptr[node + 1];
    float agg = 0.0f;
    for (int eb = start; eb < end; eb += 64) {
        int cnt = min(64, end - eb);
        int s = (lane < cnt) ? col[eb + lane] : 0;
        for (int j = 0; j < cnt; j++) {
            int sj = __shfl(s, j, 64);
            agg += xin[(long)sj * D + lane];
        }
    }

    float h = (1.0f + *epsp) * xin[base + lane] + agg;
    sh[w][lane] = h;
    __syncthreads();

    // y1 = silu(h @ W1 + b1)
    float a1 = b1[lane];
#pragma unroll
    for (int k = 0; k < D; k++) a1 += sh[w][k] * W1[k * D + lane];
    a1 = a1 / (1.0f + __expf(-a1));

    __syncthreads();
    sh[w][lane] = a1;
    __syncthreads();

    // y2 = y1 @ W2 + b2
    float a2 = b2[lane];
#pragma unroll
    for (int k = 0; k < D; k++) a2 += sh[w][k] * W2[k * D + lane];

    // LayerNorm over 64 lanes
    float s = a2;
#pragma unroll
    for (int m = 32; m >= 1; m >>= 1) s += __shfl_xor(s, m, 64);
    float mu = s * (1.0f / 64.0f);
    float dd = a2 - mu;
    float v = dd * dd;
#pragma unroll
    for (int m = 32; m >= 1; m >>= 1) v += __shfl_xor(v, m, 64);
    float inv = rsqrtf(v * (1.0f / 64.0f) + LN_EPS);
    xout[base + lane] = dd * inv * lng[lane] + lnb[lane];
}

// ---------------- gate MLP: gate[n] = gw2 . silu(x gw1 + gb1) + gb2 ----------------
__global__ __launch_bounds__(256) void k_gate(const float* __restrict__ xf,
                                              const float* __restrict__ gw1,
                                              const float* __restrict__ gb1,
                                              const float* __restrict__ gw2,
                                              const float* __restrict__ gb2,
                                              float* __restrict__ gate) {
    __shared__ float sh[4][D];
    int w = threadIdx.x >> 6;
    int lane = threadIdx.x & 63;
    int node = blockIdx.x * 4 + w;
    sh[w][lane] = xf[(long)node * D + lane];
    __syncthreads();

    float c = 0.0f;
    if (lane < 32) {
        float a = gb1[lane];
#pragma unroll
        for (int k = 0; k < D; k++) a += sh[w][k] * gw1[k * 32 + lane];
        a = a / (1.0f + __expf(-a));
        c = a * gw2[lane];
    }
#pragma unroll
    for (int m = 32; m >= 1; m >>= 1) c += __shfl_xor(c, m, 64);
    if (lane == 0) gate[node] = c + gb2[0];
}

// ---------------- per-graph softmax pooling ----------------
__global__ __launch_bounds__(64) void k_pool(const float* __restrict__ xf,
                                             const float* __restrict__ gate,
                                             const int* __restrict__ batch,
                                             float* __restrict__ out) {
    int g = blockIdx.x;
    int lane = threadIdx.x;

    int lo = 0, hi = NN;
    while (lo < hi) { int mid = (lo + hi) >> 1; if (batch[mid] < g) lo = mid + 1; else hi = mid; }
    int start = lo;
    hi = NN;
    while (lo < hi) { int mid = (lo + hi) >> 1; if (batch[mid] < g + 1) lo = mid + 1; else hi = mid; }
    int end = lo;

    if (start >= end) { out[(long)g * D + lane] = 0.0f; return; }

    float m = -INFINITY;
    for (int n = start + lane; n < end; n += 64) m = fmaxf(m, gate[n]);
#pragma unroll
    for (int mm = 32; mm >= 1; mm >>= 1) m = fmaxf(m, __shfl_xor(m, mm, 64));

    float s = 0.0f;
    for (int n = start + lane; n < end; n += 64) s += __expf(gate[n] - m);
#pragma unroll
    for (int mm = 32; mm >= 1; mm >>= 1) s += __shfl_xor(s, mm, 64);

    float acc = 0.0f;
    for (int n = start; n < end; n++) acc += __expf(gate[n] - m) * xf[(long)n * D + lane];

    out[(long)g * D + lane] = acc / s;
}

extern "C" void kernel_launch(void* const* d_in, const int* in_sizes, int n_in,
                              void* d_out, int out_size, void* d_ws, size_t ws_size,
                              hipStream_t stream) {
    const float* x   = (const float*)d_in[0];
    const int* ei    = (const int*)d_in[1];
    const int* batch = (const int*)d_in[2];
    const float* W1  = (const float*)d_in[3];
    const float* b1  = (const float*)d_in[4];
    const float* W2  = (const float*)d_in[5];
    const float* b2  = (const float*)d_in[6];
    const float* eps = (const float*)d_in[7];
    const float* lng = (const float*)d_in[8];
    const float* lnb = (const float*)d_in[9];
    const float* gw1 = (const float*)d_in[10];
    const float* gb1 = (const float*)d_in[11];
    const float* gw2 = (const float*)d_in[12];
    const float* gb2 = (const float*)d_in[13];

    const int* src = ei;
    const int* dst = ei + NE;

    // workspace layout
    float* xa      = (float*)d_ws;                 // NN*D floats (ping)
    float* xb      = xa + (long)NN * D;            // NN*D floats (pong)
    float* gate    = xb + (long)NN * D;            // NN floats
    int*   counts  = (int*)(gate + NN);            // NN ints
    int*   row_ptr = counts + NN;                  // NN+1 ints
    int*   cursor  = row_ptr + NN + 1;             // NN ints
    int*   col     = cursor + NN;                  // NE ints

    float* out = (float*)d_out;                    // fp32 [G, D]

    // ---- build CSR (dst-indexed) once; reused for all 3 layers ----
    hipMemsetAsync(counts, 0, (size_t)NN * sizeof(int), stream);
    k_hist<<<NE / 256, 256, 0, stream>>>(dst, counts);
    k_scan<<<1, SCAN_T, 0, stream>>>(counts, row_ptr);
    hipMemcpyAsync(cursor, row_ptr, (size_t)NN * sizeof(int),
                   hipMemcpyDeviceToDevice, stream);
    k_fill<<<NE / 256, 256, 0, stream>>>(src, dst, cursor, col);

    // ---- 3 GIN layers, ping-pong xa/xb ----
    const float* xin = x;
    float* xout = xa;
    for (int l = 0; l < NL; l++) {
        k_fused<<<NN / 4, 256, 0, stream>>>(xin, xout, row_ptr, col,
                                            W1 + (long)l * D * D, b1 + (long)l * D,
                                            W2 + (long)l * D * D, b2 + (long)l * D,
                                            eps + l, lng + (long)l * D, lnb + (long)l * D);
        xin = xout;
        xout = (xout == xa) ? xb : xa;
    }
    const float* xf = xin;  // final features

    k_gate<<<NN / 4, 256, 0, stream>>>(xf, gw1, gb1, gw2, gb2, gate);
    k_pool<<<NG, 64, 0, stream>>>(xf, gate, batch, out);
}

// Round 5
// 1052.053 us; speedup vs baseline: 4.4446x; 1.2059x over previous
//
#include <hip/hip_runtime.h>
#include <math.h>

#define NN 100000
#define NE 1600000
#define D 64
#define NL 3
#define NG 2000
#define LN_EPS 1e-5f

#define NB ((NN + 255) / 256)   // 391 scan blocks

// ---------------- CSR build: histogram of dst ----------------
__global__ __launch_bounds__(256) void k_hist(const int* __restrict__ dst,
                                              int* __restrict__ counts) {
    int e = blockIdx.x * 256 + threadIdx.x;
    atomicAdd(&counts[dst[e]], 1);
}

// ---------------- CSR build: per-block sums (coalesced) ----------------
__global__ __launch_bounds__(256) void k_bsum(const int* __restrict__ counts,
                                              int* __restrict__ bsum) {
    __shared__ int red[4];
    int i = blockIdx.x * 256 + threadIdx.x;
    int v = (i < NN) ? counts[i] : 0;
#pragma unroll
    for (int m = 32; m >= 1; m >>= 1) v += __shfl_xor(v, m, 64);
    if ((threadIdx.x & 63) == 0) red[threadIdx.x >> 6] = v;
    __syncthreads();
    if (threadIdx.x == 0) bsum[blockIdx.x] = red[0] + red[1] + red[2] + red[3];
}

// ---------------- CSR build: scan the 391 block sums (single block) ----------------
__global__ __launch_bounds__(512) void k_bscan(const int* __restrict__ bsum,
                                               int* __restrict__ bbase) {
    __shared__ int s[512];
    int t = threadIdx.x;
    int v = (t < NB) ? bsum[t] : 0;
    s[t] = v;
    __syncthreads();
    for (int off = 1; off < 512; off <<= 1) {
        int u = (t >= off) ? s[t - off] : 0;
        __syncthreads();
        s[t] += u;
        __syncthreads();
    }
    if (t < NB) bbase[t] = s[t] - v;  // exclusive base
}

// ---------------- CSR build: block-local exclusive scan + base ----------------
__global__ __launch_bounds__(256) void k_apply(const int* __restrict__ counts,
                                               const int* __restrict__ bbase,
                                               int* __restrict__ row_ptr) {
    __shared__ int wsum[4];
    int i = blockIdx.x * 256 + threadIdx.x;
    int lane = threadIdx.x & 63;
    int w = threadIdx.x >> 6;
    int v = (i < NN) ? counts[i] : 0;
    int x = v;
#pragma unroll
    for (int off = 1; off < 64; off <<= 1) {
        int u = __shfl_up(x, off, 64);
        if (lane >= off) x += u;
    }
    if (lane == 63) wsum[w] = x;
    __syncthreads();
    int base = bbase[blockIdx.x];
    for (int k = 0; k < w; k++) base += wsum[k];
    if (i < NN) row_ptr[i] = base + x - v;
    if (i == 0) row_ptr[NN] = NE;
}

// ---------------- CSR build: fill col with src per dst-slot ----------------
__global__ __launch_bounds__(256) void k_fill(const int* __restrict__ src,
                                              const int* __restrict__ dst,
                                              int* __restrict__ cursor,
                                              int* __restrict__ col) {
    int e = blockIdx.x * 256 + threadIdx.x;
    int pos = atomicAdd(&cursor[dst[e]], 1);
    col[pos] = src[e];
}

// ---------------- fused gather + GIN + MLP + LN (+ gate on last layer) ----------------
// block = 256 = 4 waves; each wave owns 4 nodes; lane = feature.
// LDS rows are wave-private -> NO __syncthreads needed.
template <int LAST>
__global__ __launch_bounds__(256) void k_fused(const float* __restrict__ xin,
                                               float* __restrict__ xout,
                                               const int* __restrict__ row_ptr,
                                               const int* __restrict__ col,
                                               const float* __restrict__ W1,
                                               const float* __restrict__ b1,
                                               const float* __restrict__ W2,
                                               const float* __restrict__ b2,
                                               const float* __restrict__ epsp,
                                               const float* __restrict__ lng,
                                               const float* __restrict__ lnb,
                                               const float* __restrict__ gw1,
                                               const float* __restrict__ gb1,
                                               const float* __restrict__ gw2,
                                               const float* __restrict__ gb2,
                                               float* __restrict__ gate) {
    __shared__ float sh[16][D];
    int w = threadIdx.x >> 6;
    int lane = threadIdx.x & 63;
    int node0 = blockIdx.x * 16 + w * 4;

    float epsv = 1.0f + *epsp;

    // ---- gather + GIN update for 4 nodes ----
#pragma unroll
    for (int n = 0; n < 4; n++) {
        int node = node0 + n;
        int start = row_ptr[node];
        int end = row_ptr[node + 1];
        float s0 = 0.f, s1 = 0.f, s2 = 0.f, s3 = 0.f;
        for (int eb = start; eb < end; eb += 64) {
            int cnt = min(64, end - eb);
            int c = (lane < cnt) ? col[eb + lane] : 0;
            int j = 0;
            for (; j + 4 <= cnt; j += 4) {
                int i0 = __shfl(c, j, 64), i1 = __shfl(c, j + 1, 64);
                int i2 = __shfl(c, j + 2, 64), i3 = __shfl(c, j + 3, 64);
                s0 += xin[((size_t)i0 << 6) + lane];
                s1 += xin[((size_t)i1 << 6) + lane];
                s2 += xin[((size_t)i2 << 6) + lane];
                s3 += xin[((size_t)i3 << 6) + lane];
            }
            for (; j < cnt; j++)
                s0 += xin[((size_t)__shfl(c, j, 64) << 6) + lane];
        }
        float h = epsv * xin[((size_t)node << 6) + lane] + ((s0 + s1) + (s2 + s3));
        sh[w * 4 + n][lane] = h;
    }

    const float4* r0 = (const float4*)sh[w * 4 + 0];
    const float4* r1 = (const float4*)sh[w * 4 + 1];
    const float4* r2 = (const float4*)sh[w * 4 + 2];
    const float4* r3 = (const float4*)sh[w * 4 + 3];

    // ---- MLP layer 1: a = h @ W1 + b1 ----
    float bv = b1[lane];
    float a0 = bv, a1 = bv, a2 = bv, a3 = bv;
#pragma unroll
    for (int q = 0; q < 16; q++) {
        float4 h0 = r0[q], h1 = r1[q], h2 = r2[q], h3 = r3[q];
        float w0 = W1[(4 * q + 0) * D + lane];
        float w1 = W1[(4 * q + 1) * D + lane];
        float w2 = W1[(4 * q + 2) * D + lane];
        float w3 = W1[(4 * q + 3) * D + lane];
        a0 = fmaf(h0.x, w0, a0); a0 = fmaf(h0.y, w1, a0); a0 = fmaf(h0.z, w2, a0); a0 = fmaf(h0.w, w3, a0);
        a1 = fmaf(h1.x, w0, a1); a1 = fmaf(h1.y, w1, a1); a1 = fmaf(h1.z, w2, a1); a1 = fmaf(h1.w, w3, a1);
        a2 = fmaf(h2.x, w0, a2); a2 = fmaf(h2.y, w1, a2); a2 = fmaf(h2.z, w2, a2); a2 = fmaf(h2.w, w3, a2);
        a3 = fmaf(h3.x, w0, a3); a3 = fmaf(h3.y, w1, a3); a3 = fmaf(h3.z, w2, a3); a3 = fmaf(h3.w, w3, a3);
    }
    a0 = a0 / (1.0f + __expf(-a0));
    a1 = a1 / (1.0f + __expf(-a1));
    a2 = a2 / (1.0f + __expf(-a2));
    a3 = a3 / (1.0f + __expf(-a3));
    sh[w * 4 + 0][lane] = a0;
    sh[w * 4 + 1][lane] = a1;
    sh[w * 4 + 2][lane] = a2;
    sh[w * 4 + 3][lane] = a3;

    // ---- MLP layer 2: y = a @ W2 + b2 ----
    float cv = b2[lane];
    float y0 = cv, y1 = cv, y2 = cv, y3 = cv;
#pragma unroll
    for (int q = 0; q < 16; q++) {
        float4 h0 = r0[q], h1 = r1[q], h2 = r2[q], h3 = r3[q];
        float w0 = W2[(4 * q + 0) * D + lane];
        float w1 = W2[(4 * q + 1) * D + lane];
        float w2 = W2[(4 * q + 2) * D + lane];
        float w3 = W2[(4 * q + 3) * D + lane];
        y0 = fmaf(h0.x, w0, y0); y0 = fmaf(h0.y, w1, y0); y0 = fmaf(h0.z, w2, y0); y0 = fmaf(h0.w, w3, y0);
        y1 = fmaf(h1.x, w0, y1); y1 = fmaf(h1.y, w1, y1); y1 = fmaf(h1.z, w2, y1); y1 = fmaf(h1.w, w3, y1);
        y2 = fmaf(h2.x, w0, y2); y2 = fmaf(h2.y, w1, y2); y2 = fmaf(h2.z, w2, y2); y2 = fmaf(h2.w, w3, y2);
        y3 = fmaf(h3.x, w0, y3); y3 = fmaf(h3.y, w1, y3); y3 = fmaf(h3.z, w2, y3); y3 = fmaf(h3.w, w3, y3);
    }

    // ---- LayerNorm per node (+ stash for gate) ----
    float yy[4] = {y0, y1, y2, y3};
    float gv = lng[lane], bb = lnb[lane];
#pragma unroll
    for (int n = 0; n < 4; n++) {
        float s = yy[n];
#pragma unroll
        for (int m = 32; m >= 1; m >>= 1) s += __shfl_xor(s, m, 64);
        float mu = s * (1.0f / 64.0f);
        float dd = yy[n] - mu;
        float vv = dd * dd;
#pragma unroll
        for (int m = 32; m >= 1; m >>= 1) vv += __shfl_xor(vv, m, 64);
        float inv = rsqrtf(vv * (1.0f / 64.0f) + LN_EPS);
        float xo = dd * inv * gv + bb;
        xout[((size_t)(node0 + n) << 6) + lane] = xo;
        if (LAST) sh[w * 4 + n][lane] = xo;
    }

    // ---- gate MLP fused into last layer ----
    if (LAST) {
        int l2 = lane & 31;
        float hb = gb1[l2];
        float g0 = hb, g1 = hb, g2 = hb, g3 = hb;
#pragma unroll
        for (int q = 0; q < 16; q++) {
            float4 x0 = r0[q], x1 = r1[q], x2 = r2[q], x3 = r3[q];
            float w0 = gw1[(4 * q + 0) * 32 + l2];
            float w1 = gw1[(4 * q + 1) * 32 + l2];
            float w2 = gw1[(4 * q + 2) * 32 + l2];
            float w3 = gw1[(4 * q + 3) * 32 + l2];
            g0 = fmaf(x0.x, w0, g0); g0 = fmaf(x0.y, w1, g0); g0 = fmaf(x0.z, w2, g0); g0 = fmaf(x0.w, w3, g0);
            g1 = fmaf(x1.x, w0, g1); g1 = fmaf(x1.y, w1, g1); g1 = fmaf(x1.z, w2, g1); g1 = fmaf(x1.w, w3, g1);
            g2 = fmaf(x2.x, w0, g2); g2 = fmaf(x2.y, w1, g2); g2 = fmaf(x2.z, w2, g2); g2 = fmaf(x2.w, w3, g2);
            g3 = fmaf(x3.x, w0, g3); g3 = fmaf(x3.y, w1, g3); g3 = fmaf(x3.z, w2, g3); g3 = fmaf(x3.w, w3, g3);
        }
        float gwv = gw2[l2];
        float gg[4] = {g0, g1, g2, g3};
#pragma unroll
        for (int n = 0; n < 4; n++) {
            float t = gg[n];
            t = t / (1.0f + __expf(-t));
            float c = (lane < 32) ? t * gwv : 0.0f;
#pragma unroll
            for (int m = 32; m >= 1; m >>= 1) c += __shfl_xor(c, m, 64);
            if (lane == 0) gate[node0 + n] = c + gb2[0];
        }
    }
}

// ---------------- per-graph softmax pooling ----------------
__global__ __launch_bounds__(64) void k_pool(const float* __restrict__ xf,
                                             const float* __restrict__ gate,
                                             const int* __restrict__ batch,
                                             float* __restrict__ out) {
    int g = blockIdx.x;
    int lane = threadIdx.x;

    int lo = 0, hi = NN;
    while (lo < hi) { int mid = (lo + hi) >> 1; if (batch[mid] < g) lo = mid + 1; else hi = mid; }
    int start = lo;
    hi = NN;
    while (lo < hi) { int mid = (lo + hi) >> 1; if (batch[mid] < g + 1) lo = mid + 1; else hi = mid; }
    int end = lo;

    if (start >= end) { out[((size_t)g << 6) + lane] = 0.0f; return; }

    float m = -INFINITY;
    for (int n = start + lane; n < end; n += 64) m = fmaxf(m, gate[n]);
#pragma unroll
    for (int mm = 32; mm >= 1; mm >>= 1) m = fmaxf(m, __shfl_xor(m, mm, 64));

    float s = 0.0f;
    for (int n = start + lane; n < end; n += 64) s += __expf(gate[n] - m);
#pragma unroll
    for (int mm = 32; mm >= 1; mm >>= 1) s += __shfl_xor(s, mm, 64);

    float acc0 = 0.f, acc1 = 0.f, acc2 = 0.f, acc3 = 0.f;
    int n = start;
    for (; n + 4 <= end; n += 4) {
        float e0 = __expf(gate[n] - m), e1 = __expf(gate[n + 1] - m);
        float e2 = __expf(gate[n + 2] - m), e3 = __expf(gate[n + 3] - m);
        acc0 += e0 * xf[((size_t)n << 6) + lane];
        acc1 += e1 * xf[((size_t)(n + 1) << 6) + lane];
        acc2 += e2 * xf[((size_t)(n + 2) << 6) + lane];
        acc3 += e3 * xf[((size_t)(n + 3) << 6) + lane];
    }
    for (; n < end; n++) acc0 += __expf(gate[n] - m) * xf[((size_t)n << 6) + lane];

    out[((size_t)g << 6) + lane] = ((acc0 + acc1) + (acc2 + acc3)) / s;
}

extern "C" void kernel_launch(void* const* d_in, const int* in_sizes, int n_in,
                              void* d_out, int out_size, void* d_ws, size_t ws_size,
                              hipStream_t stream) {
    const float* x   = (const float*)d_in[0];
    const int* ei    = (const int*)d_in[1];
    const int* batch = (const int*)d_in[2];
    const float* W1  = (const float*)d_in[3];
    const float* b1  = (const float*)d_in[4];
    const float* W2  = (const float*)d_in[5];
    const float* b2  = (const float*)d_in[6];
    const float* eps = (const float*)d_in[7];
    const float* lng = (const float*)d_in[8];
    const float* lnb = (const float*)d_in[9];
    const float* gw1 = (const float*)d_in[10];
    const float* gb1 = (const float*)d_in[11];
    const float* gw2 = (const float*)d_in[12];
    const float* gb2 = (const float*)d_in[13];

    const int* src = ei;
    const int* dst = ei + NE;

    // workspace layout
    float* xa      = (float*)d_ws;                 // NN*D floats (ping)
    float* xb      = xa + (size_t)NN * D;          // NN*D floats (pong)
    float* gate    = xb + (size_t)NN * D;          // NN floats
    int*   counts  = (int*)(gate + NN);            // NN ints
    int*   row_ptr = counts + NN;                  // NN+1 ints
    int*   cursor  = row_ptr + NN + 1;             // NN ints
    int*   col     = cursor + NN;                  // NE ints
    int*   bsum    = col + NE;                     // NB ints
    int*   bbase   = bsum + NB;                    // NB ints

    float* out = (float*)d_out;                    // fp32 [G, D]

    // ---- build CSR (dst-indexed) once; reused for all 3 layers ----
    hipMemsetAsync(counts, 0, (size_t)NN * sizeof(int), stream);
    k_hist<<<NE / 256, 256, 0, stream>>>(dst, counts);
    k_bsum<<<NB, 256, 0, stream>>>(counts, bsum);
    k_bscan<<<1, 512, 0, stream>>>(bsum, bbase);
    k_apply<<<NB, 256, 0, stream>>>(counts, bbase, row_ptr);
    hipMemcpyAsync(cursor, row_ptr, (size_t)NN * sizeof(int),
                   hipMemcpyDeviceToDevice, stream);
    k_fill<<<NE / 256, 256, 0, stream>>>(src, dst, cursor, col);

    // ---- 3 GIN layers, ping-pong xa/xb (gate fused into last) ----
    k_fused<0><<<NN / 16, 256, 0, stream>>>(x,  xa, row_ptr, col,
        W1 + 0 * D * D, b1 + 0 * D, W2 + 0 * D * D, b2 + 0 * D,
        eps + 0, lng + 0 * D, lnb + 0 * D, gw1, gb1, gw2, gb2, gate);
    k_fused<0><<<NN / 16, 256, 0, stream>>>(xa, xb, row_ptr, col,
        W1 + 1 * D * D, b1 + 1 * D, W2 + 1 * D * D, b2 + 1 * D,
        eps + 1, lng + 1 * D, lnb + 1 * D, gw1, gb1, gw2, gb2, gate);
    k_fused<1><<<NN / 16, 256, 0, stream>>>(xb, xa, row_ptr, col,
        W1 + 2 * D * D, b1 + 2 * D, W2 + 2 * D * D, b2 + 2 * D,
        eps + 2, lng + 2 * D, lnb + 2 * D, gw1, gb1, gw2, gb2, gate);

    k_pool<<<NG, 64, 0, stream>>>(xa, gate, batch, out);
}

// Round 6
// 537.092 us; speedup vs baseline: 8.7061x; 1.9588x over previous
//
#include <hip/hip_runtime.h>
#include <math.h>

#define NN 100000
#define NE 1600000
#define D 64
#define NG 2000
#define LN_EPS 1e-5f
#define NB ((NN + 255) / 256)        // 391
#define NTILE ((NN + 63) / 64)       // 1563

typedef __attribute__((ext_vector_type(8))) short short8;   // 8 bf16 in 4 VGPRs
typedef __attribute__((ext_vector_type(4))) float floatx4;  // MFMA accumulator

__device__ __forceinline__ unsigned short f2bf(float f) {
    unsigned int u = __float_as_uint(f);
    u += 0x7FFF + ((u >> 16) & 1);   // round-to-nearest-even
    return (unsigned short)(u >> 16);
}

// ================= CSR build =================
__global__ __launch_bounds__(256) void k_hist(const int* __restrict__ dst,
                                              int* __restrict__ counts) {
    int e = blockIdx.x * 256 + threadIdx.x;
    atomicAdd(&counts[dst[e]], 1);
}

__global__ __launch_bounds__(256) void k_bsum(const int* __restrict__ counts,
                                              int* __restrict__ bsum) {
    __shared__ int red[4];
    int i = blockIdx.x * 256 + threadIdx.x;
    int v = (i < NN) ? counts[i] : 0;
#pragma unroll
    for (int m = 32; m >= 1; m >>= 1) v += __shfl_xor(v, m, 64);
    if ((threadIdx.x & 63) == 0) red[threadIdx.x >> 6] = v;
    __syncthreads();
    if (threadIdx.x == 0) bsum[blockIdx.x] = red[0] + red[1] + red[2] + red[3];
}

__global__ __launch_bounds__(512) void k_bscan(const int* __restrict__ bsum,
                                               int* __restrict__ bbase) {
    __shared__ int s[512];
    int t = threadIdx.x;
    int v = (t < NB) ? bsum[t] : 0;
    s[t] = v;
    __syncthreads();
    for (int off = 1; off < 512; off <<= 1) {
        int u = (t >= off) ? s[t - off] : 0;
        __syncthreads();
        s[t] += u;
        __syncthreads();
    }
    if (t < NB) bbase[t] = s[t] - v;
}

__global__ __launch_bounds__(256) void k_apply(const int* __restrict__ counts,
                                               const int* __restrict__ bbase,
                                               int* __restrict__ row_ptr) {
    __shared__ int wsum[4];
    int i = blockIdx.x * 256 + threadIdx.x;
    int lane = threadIdx.x & 63;
    int w = threadIdx.x >> 6;
    int v = (i < NN) ? counts[i] : 0;
    int x = v;
#pragma unroll
    for (int off = 1; off < 64; off <<= 1) {
        int u = __shfl_up(x, off, 64);
        if (lane >= off) x += u;
    }
    if (lane == 63) wsum[w] = x;
    __syncthreads();
    int base = bbase[blockIdx.x];
    for (int k = 0; k < w; k++) base += wsum[k];
    if (i < NN) row_ptr[i] = base + x - v;
    if (i == 0) row_ptr[NN] = NE;
}

__global__ __launch_bounds__(256) void k_fill(const int* __restrict__ src,
                                              const int* __restrict__ dst,
                                              int* __restrict__ cursor,
                                              int* __restrict__ col) {
    int e = blockIdx.x * 256 + threadIdx.x;
    int pos = atomicAdd(&cursor[dst[e]], 1);
    col[pos] = src[e];
}

// ================= gather: h = (1+eps)x + sum_neighbors, bf16 out =================
// wave per node (max TLP, tiny VGPR footprint)
__global__ __launch_bounds__(256) void k_gather(const float* __restrict__ xin,
                                                unsigned short* __restrict__ h,
                                                const int* __restrict__ row_ptr,
                                                const int* __restrict__ col,
                                                const float* __restrict__ epsp) {
    int w = threadIdx.x >> 6;
    int lane = threadIdx.x & 63;
    int node = blockIdx.x * 4 + w;
    int start = row_ptr[node], end = row_ptr[node + 1];
    float s0 = 0.f, s1 = 0.f, s2 = 0.f, s3 = 0.f;
    for (int eb = start; eb < end; eb += 64) {
        int cnt = min(64, end - eb);
        int c = (lane < cnt) ? col[eb + lane] : 0;
        int j = 0;
        for (; j + 4 <= cnt; j += 4) {
            int i0 = __shfl(c, j, 64), i1 = __shfl(c, j + 1, 64);
            int i2 = __shfl(c, j + 2, 64), i3 = __shfl(c, j + 3, 64);
            s0 += xin[((size_t)i0 << 6) + lane];
            s1 += xin[((size_t)i1 << 6) + lane];
            s2 += xin[((size_t)i2 << 6) + lane];
            s3 += xin[((size_t)i3 << 6) + lane];
        }
        for (; j < cnt; j++)
            s0 += xin[((size_t)__shfl(c, j, 64) << 6) + lane];
    }
    float hv = (1.0f + *epsp) * xin[((size_t)node << 6) + lane] + ((s0 + s1) + (s2 + s3));
    h[((size_t)node << 6) + lane] = f2bf(hv);
}

// ================= MFMA MLP + LN (+ fused gate on last layer) =================
// block = 4 waves = 64-node tile; each wave owns 16 nodes (M=16).
// Layouts (gfx950, 16x16x32 bf16): A[m=lane&15][k=quad*8+j]
//   B[k=quad*8+j][n=lane&15]   C/D col=lane&15, row=quad*4+reg
template <int LAST>
__global__ __launch_bounds__(256) void k_mfma(const unsigned short* __restrict__ h,
                                              float* __restrict__ xout,
                                              const float* __restrict__ W1,
                                              const float* __restrict__ b1,
                                              const float* __restrict__ W2,
                                              const float* __restrict__ b2,
                                              const float* __restrict__ lng,
                                              const float* __restrict__ lnb,
                                              const float* __restrict__ gw1,
                                              const float* __restrict__ gb1,
                                              const float* __restrict__ gw2,
                                              const float* __restrict__ gb2,
                                              float* __restrict__ gate) {
    __shared__ unsigned short a2[4][16 * 64];   // per-wave 16x64 bf16 staging
    int w = threadIdx.x >> 6;
    int lane = threadIdx.x & 63;
    int n = lane & 15;
    int q = lane >> 4;
    int base = blockIdx.x * 64 + w * 16;

    // ---- weight B-fragments (bf16, registers) ----
    short8 B1f[2][4], B2f[2][4];
#pragma unroll
    for (int ks = 0; ks < 2; ks++)
#pragma unroll
        for (int c = 0; c < 4; c++) {
            short8 f1, f2;
#pragma unroll
            for (int j = 0; j < 8; j++) {
                int k = ks * 32 + q * 8 + j;
                f1[j] = (short)f2bf(W1[k * 64 + c * 16 + n]);
                f2[j] = (short)f2bf(W2[k * 64 + c * 16 + n]);
            }
            B1f[ks][c] = f1;
            B2f[ks][c] = f2;
        }

    // per-lane params
    float b1v[4], b2v[4], lgv[4], lbv[4];
#pragma unroll
    for (int c = 0; c < 4; c++) {
        b1v[c] = b1[c * 16 + n];
        b2v[c] = b2[c * 16 + n];
        lgv[c] = lng[c * 16 + n];
        lbv[c] = lnb[c * 16 + n];
    }

    // ---- A fragments from h (direct bf16 16B loads) ----
    int mnode = base + n;
    int mc = min(mnode, NN - 1);
    const short8* hp = (const short8*)(h + ((size_t)mc << 6));
    short8 A0 = hp[q];        // k = q*8..q*8+7
    short8 A1 = hp[4 + q];    // k = 32+q*8..

    // ---- GEMM1: C1 = h @ W1 + b1 ----
    floatx4 acc1[4];
#pragma unroll
    for (int c = 0; c < 4; c++) {
        floatx4 a = {b1v[c], b1v[c], b1v[c], b1v[c]};
        a = __builtin_amdgcn_mfma_f32_16x16x32_bf16(A0, B1f[0][c], a, 0, 0, 0);
        a = __builtin_amdgcn_mfma_f32_16x16x32_bf16(A1, B1f[1][c], a, 0, 0, 0);
        acc1[c] = a;
    }

    // ---- silu -> LDS (C-layout -> A-layout round trip) ----
    unsigned short* aw = a2[w];
#pragma unroll
    for (int c = 0; c < 4; c++)
#pragma unroll
        for (int r = 0; r < 4; r++) {
            float v = acc1[c][r];
            v = v / (1.0f + __expf(-v));
            aw[(q * 4 + r) * 64 + c * 16 + n] = f2bf(v);
        }

    const short8* ap = (const short8*)(aw + n * 64);
    short8 A20 = ap[q];
    short8 A21 = ap[4 + q];

    // ---- GEMM2: C2 = silu(C1) @ W2 + b2 ----
    floatx4 acc2[4];
#pragma unroll
    for (int c = 0; c < 4; c++) {
        floatx4 a = {b2v[c], b2v[c], b2v[c], b2v[c]};
        a = __builtin_amdgcn_mfma_f32_16x16x32_bf16(A20, B2f[0][c], a, 0, 0, 0);
        a = __builtin_amdgcn_mfma_f32_16x16x32_bf16(A21, B2f[1][c], a, 0, 0, 0);
        acc2[c] = a;
    }

    // ---- LayerNorm across the 64 cols of each row ----
    float mu[4], inv[4];
#pragma unroll
    for (int r = 0; r < 4; r++) {
        float s = acc2[0][r] + acc2[1][r] + acc2[2][r] + acc2[3][r];
#pragma unroll
        for (int off = 1; off < 16; off <<= 1) s += __shfl_xor(s, off, 64);
        mu[r] = s * (1.0f / 64.0f);
        float d0 = acc2[0][r] - mu[r], d1 = acc2[1][r] - mu[r];
        float d2 = acc2[2][r] - mu[r], d3 = acc2[3][r] - mu[r];
        float vv = d0 * d0 + d1 * d1 + d2 * d2 + d3 * d3;
#pragma unroll
        for (int off = 1; off < 16; off <<= 1) vv += __shfl_xor(vv, off, 64);
        inv[r] = rsqrtf(vv * (1.0f / 64.0f) + LN_EPS);
    }

    // ---- store fp32 (+ stash bf16 for gate) ----
#pragma unroll
    for (int c = 0; c < 4; c++)
#pragma unroll
        for (int r = 0; r < 4; r++) {
            int node = base + q * 4 + r;
            float o = (acc2[c][r] - mu[r]) * inv[r] * lgv[c] + lbv[c];
            if (node < NN) xout[((size_t)node << 6) + c * 16 + n] = o;
            if (LAST) aw[(q * 4 + r) * 64 + c * 16 + n] = f2bf(o);
        }

    // ---- fused gate MLP (last layer): gate = silu(x@gw1+gb1)@gw2 + gb2 ----
    if (LAST) {
        short8 B3f[2][2];
#pragma unroll
        for (int ks = 0; ks < 2; ks++)
#pragma unroll
            for (int c = 0; c < 2; c++) {
                short8 f;
#pragma unroll
                for (int j = 0; j < 8; j++) {
                    int k = ks * 32 + q * 8 + j;
                    f[j] = (short)f2bf(gw1[k * 32 + c * 16 + n]);
                }
                B3f[ks][c] = f;
            }
        const short8* gp = (const short8*)(aw + n * 64);
        short8 G0 = gp[q];
        short8 G1 = gp[4 + q];
        floatx4 acc3[2];
#pragma unroll
        for (int c = 0; c < 2; c++) {
            float bv = gb1[c * 16 + n];
            floatx4 a = {bv, bv, bv, bv};
            a = __builtin_amdgcn_mfma_f32_16x16x32_bf16(G0, B3f[0][c], a, 0, 0, 0);
            a = __builtin_amdgcn_mfma_f32_16x16x32_bf16(G1, B3f[1][c], a, 0, 0, 0);
            acc3[c] = a;
        }
        float gw2v0 = gw2[n], gw2v1 = gw2[16 + n];
        float gb2v = gb2[0];
#pragma unroll
        for (int r = 0; r < 4; r++) {
            float v0 = acc3[0][r];
            v0 = v0 / (1.0f + __expf(-v0));
            float v1 = acc3[1][r];
            v1 = v1 / (1.0f + __expf(-v1));
            float gsum = v0 * gw2v0 + v1 * gw2v1;
#pragma unroll
            for (int off = 1; off < 16; off <<= 1) gsum += __shfl_xor(gsum, off, 64);
            int node = base + q * 4 + r;
            if (n == 0 && node < NN) gate[node] = gsum + gb2v;
        }
    }
}

// ================= per-graph softmax pooling (4 waves per graph) =================
__global__ __launch_bounds__(256) void k_pool(const float* __restrict__ xf,
                                              const float* __restrict__ gate,
                                              const int* __restrict__ batch,
                                              float* __restrict__ out) {
    __shared__ float redm[4];
    __shared__ float reds[4];
    __shared__ float racc[4][D];
    int g = blockIdx.x;
    int w = threadIdx.x >> 6;
    int lane = threadIdx.x & 63;

    int lo = 0, hi = NN;
    while (lo < hi) { int mid = (lo + hi) >> 1; if (batch[mid] < g) lo = mid + 1; else hi = mid; }
    int start = lo;
    hi = NN;
    while (lo < hi) { int mid = (lo + hi) >> 1; if (batch[mid] < g + 1) lo = mid + 1; else hi = mid; }
    int end = lo;

    if (start >= end) {
        if (w == 0) out[((size_t)g << 6) + lane] = 0.0f;
        return;
    }

    // block max
    float m = -INFINITY;
    for (int i = start + (int)threadIdx.x; i < end; i += 256) m = fmaxf(m, gate[i]);
#pragma unroll
    for (int mm = 32; mm >= 1; mm >>= 1) m = fmaxf(m, __shfl_xor(m, mm, 64));
    if (lane == 0) redm[w] = m;
    __syncthreads();
    m = fmaxf(fmaxf(redm[0], redm[1]), fmaxf(redm[2], redm[3]));

    // block denom
    float s = 0.0f;
    for (int i = start + (int)threadIdx.x; i < end; i += 256) s += __expf(gate[i] - m);
#pragma unroll
    for (int mm = 32; mm >= 1; mm >>= 1) s += __shfl_xor(s, mm, 64);
    if (lane == 0) reds[w] = s;
    __syncthreads();
    s = (reds[0] + reds[1]) + (reds[2] + reds[3]);

    // weighted feature sum: wave w handles nodes start+w, stride 4; lane = feature
    float acc = 0.0f;
    for (int i = start + w; i < end; i += 4)
        acc += __expf(gate[i] - m) * xf[((size_t)i << 6) + lane];
    racc[w][lane] = acc;
    __syncthreads();
    if (w == 0)
        out[((size_t)g << 6) + lane] =
            ((racc[0][lane] + racc[1][lane]) + (racc[2][lane] + racc[3][lane])) / s;
}

extern "C" void kernel_launch(void* const* d_in, const int* in_sizes, int n_in,
                              void* d_out, int out_size, void* d_ws, size_t ws_size,
                              hipStream_t stream) {
    const float* x   = (const float*)d_in[0];
    const int* ei    = (const int*)d_in[1];
    const int* batch = (const int*)d_in[2];
    const float* W1  = (const float*)d_in[3];
    const float* b1  = (const float*)d_in[4];
    const float* W2  = (const float*)d_in[5];
    const float* b2  = (const float*)d_in[6];
    const float* eps = (const float*)d_in[7];
    const float* lng = (const float*)d_in[8];
    const float* lnb = (const float*)d_in[9];
    const float* gw1 = (const float*)d_in[10];
    const float* gb1 = (const float*)d_in[11];
    const float* gw2 = (const float*)d_in[12];
    const float* gb2 = (const float*)d_in[13];

    const int* src = ei;
    const int* dst = ei + NE;

    // workspace layout (~46.5 MB)
    float* xa            = (float*)d_ws;                       // NN*64 f32
    float* gate          = xa + (size_t)NN * D;                // NN f32
    unsigned short* h    = (unsigned short*)(gate + NN);       // NN*64 bf16
    int* counts          = (int*)(h + (size_t)NN * D);         // NN
    int* row_ptr         = counts + NN;                        // NN+1
    int* cursor          = row_ptr + NN + 1;                   // NN
    int* col             = cursor + NN;                        // NE
    int* bsum            = col + NE;                           // NB
    int* bbase           = bsum + NB;                          // NB

    float* out = (float*)d_out;

    // ---- CSR build (once, reused all layers) ----
    hipMemsetAsync(counts, 0, (size_t)NN * sizeof(int), stream);
    k_hist<<<NE / 256, 256, 0, stream>>>(dst, counts);
    k_bsum<<<NB, 256, 0, stream>>>(counts, bsum);
    k_bscan<<<1, 512, 0, stream>>>(bsum, bbase);
    k_apply<<<NB, 256, 0, stream>>>(counts, bbase, row_ptr);
    hipMemcpyAsync(cursor, row_ptr, (size_t)NN * sizeof(int),
                   hipMemcpyDeviceToDevice, stream);
    k_fill<<<NE / 256, 256, 0, stream>>>(src, dst, cursor, col);

    // ---- 3 GIN layers: gather (fp32->bf16 h) then MFMA MLP (writes xa in place) ----
    k_gather<<<NN / 4, 256, 0, stream>>>(x, h, row_ptr, col, eps + 0);
    k_mfma<0><<<NTILE, 256, 0, stream>>>(h, xa,
        W1 + 0 * D * D, b1 + 0 * D, W2 + 0 * D * D, b2 + 0 * D,
        lng + 0 * D, lnb + 0 * D, gw1, gb1, gw2, gb2, gate);

    k_gather<<<NN / 4, 256, 0, stream>>>(xa, h, row_ptr, col, eps + 1);
    k_mfma<0><<<NTILE, 256, 0, stream>>>(h, xa,
        W1 + 1 * D * D, b1 + 1 * D, W2 + 1 * D * D, b2 + 1 * D,
        lng + 1 * D, lnb + 1 * D, gw1, gb1, gw2, gb2, gate);

    k_gather<<<NN / 4, 256, 0, stream>>>(xa, h, row_ptr, col, eps + 2);
    k_mfma<1><<<NTILE, 256, 0, stream>>>(h, xa,
        W1 + 2 * D * D, b1 + 2 * D, W2 + 2 * D * D, b2 + 2 * D,
        lng + 2 * D, lnb + 2 * D, gw1, gb1, gw2, gb2, gate);

    k_pool<<<NG, 256, 0, stream>>>(xa, gate, batch, out);
}

// Round 7
// 509.563 us; speedup vs baseline: 9.1765x; 1.0540x over previous
//
#include <hip/hip_runtime.h>
#include <math.h>

#define NN 100000
#define NE 1600000
#define D 64
#define NG 2000
#define LN_EPS 1e-5f
#define NB ((NN + 255) / 256)        // 391 (scan blocks == buckets)
#define NBK NB                       // buckets of 256 nodes
#define NTILE ((NN + 63) / 64)       // 1563

typedef __attribute__((ext_vector_type(8))) short short8;   // 8 bf16 in 4 VGPRs
typedef __attribute__((ext_vector_type(4))) float floatx4;  // MFMA accumulator

__device__ __forceinline__ unsigned short f2bf(float f) {
    unsigned int u = __float_as_uint(f);
    u += 0x7FFF + ((u >> 16) & 1);   // round-to-nearest-even
    return (unsigned short)(u >> 16);
}
__device__ __forceinline__ float bfu2f(unsigned short v) {
    return __uint_as_float(((unsigned int)v) << 16);
}

// ================= fp32 -> bf16 feature convert =================
__global__ __launch_bounds__(256) void k_conv(const float* __restrict__ x,
                                              unsigned short* __restrict__ xb) {
    int i = blockIdx.x * 256 + threadIdx.x;
    xb[i] = f2bf(x[i]);
}

// ================= CSR build =================
__global__ __launch_bounds__(256) void k_hist(const int* __restrict__ dst,
                                              int* __restrict__ counts) {
    int e = blockIdx.x * 256 + threadIdx.x;
    atomicAdd(&counts[dst[e]], 1);
}

__global__ __launch_bounds__(256) void k_bsum(const int* __restrict__ counts,
                                              int* __restrict__ bsum) {
    __shared__ int red[4];
    int i = blockIdx.x * 256 + threadIdx.x;
    int v = (i < NN) ? counts[i] : 0;
#pragma unroll
    for (int m = 32; m >= 1; m >>= 1) v += __shfl_xor(v, m, 64);
    if ((threadIdx.x & 63) == 0) red[threadIdx.x >> 6] = v;
    __syncthreads();
    if (threadIdx.x == 0) bsum[blockIdx.x] = red[0] + red[1] + red[2] + red[3];
}

__global__ __launch_bounds__(512) void k_bscan(const int* __restrict__ bsum,
                                               int* __restrict__ bbase) {
    __shared__ int s[512];
    int t = threadIdx.x;
    int v = (t < NB) ? bsum[t] : 0;
    s[t] = v;
    __syncthreads();
    for (int off = 1; off < 512; off <<= 1) {
        int u = (t >= off) ? s[t - off] : 0;
        __syncthreads();
        s[t] += u;
        __syncthreads();
    }
    if (t < NB) bbase[t] = s[t] - v;
}

__global__ __launch_bounds__(256) void k_apply(const int* __restrict__ counts,
                                               const int* __restrict__ bbase,
                                               int* __restrict__ row_ptr) {
    __shared__ int wsum[4];
    int i = blockIdx.x * 256 + threadIdx.x;
    int lane = threadIdx.x & 63;
    int w = threadIdx.x >> 6;
    int v = (i < NN) ? counts[i] : 0;
    int x = v;
#pragma unroll
    for (int off = 1; off < 64; off <<= 1) {
        int u = __shfl_up(x, off, 64);
        if (lane >= off) x += u;
    }
    if (lane == 63) wsum[w] = x;
    __syncthreads();
    int base = bbase[blockIdx.x];
    for (int k = 0; k < w; k++) base += wsum[k];
    if (i < NN) row_ptr[i] = base + x - v;
    if (i == 0) row_ptr[NN] = NE;
}

// bucket cursors: one per 64B line to avoid same-line atomic serialization
__global__ __launch_bounds__(512) void k_bcurinit(const int* __restrict__ row_ptr,
                                                  int* __restrict__ bcur) {
    int b = threadIdx.x;
    if (b < NBK) bcur[b * 16] = row_ptr[b * 256];
}

// phase B: partition edges into bucket-major order; 4B packed payload
__global__ __launch_bounds__(256) void k_part(const int* __restrict__ src,
                                              const int* __restrict__ dst,
                                              int* __restrict__ bcur,
                                              unsigned int* __restrict__ tmp) {
    int e = blockIdx.x * 256 + threadIdx.x;
    int d = dst[e];
    int b = d >> 8;
    int pos = atomicAdd(&bcur[b * 16], 1);
    tmp[pos] = ((unsigned int)src[e] << 8) | (unsigned int)(d & 255);
}

// phase C: per-bucket fill; scatter confined to ~16KB col window (cache-resident)
__global__ __launch_bounds__(256) void k_bfill(const unsigned int* __restrict__ tmp,
                                               const int* __restrict__ row_ptr,
                                               int* __restrict__ col) {
    __shared__ int lcur[256];
    int b = blockIdx.x;
    int nb0 = b * 256;
    int nend = min(nb0 + 256, NN);
    int cnt = nend - nb0;
    int tid = threadIdx.x;
    if (tid < cnt) lcur[tid] = row_ptr[nb0 + tid];
    __syncthreads();
    int estart = row_ptr[nb0];
    int eend = row_ptr[nend];
    for (int e = estart + tid; e < eend; e += 256) {
        unsigned int p = tmp[e];
        int pos = atomicAdd(&lcur[p & 255], 1);
        col[pos] = (int)(p >> 8);
    }
}

// ================= gather: h = (1+eps)x + sum_neighbors (bf16 in/out) =================
// wave per node (max TLP, tiny VGPR footprint)
__global__ __launch_bounds__(256) void k_gather(const unsigned short* __restrict__ xin,
                                                unsigned short* __restrict__ h,
                                                const int* __restrict__ row_ptr,
                                                const int* __restrict__ col,
                                                const float* __restrict__ epsp) {
    int w = threadIdx.x >> 6;
    int lane = threadIdx.x & 63;
    int node = blockIdx.x * 4 + w;
    int start = row_ptr[node], end = row_ptr[node + 1];
    float s0 = 0.f, s1 = 0.f, s2 = 0.f, s3 = 0.f;
    for (int eb = start; eb < end; eb += 64) {
        int cnt = min(64, end - eb);
        int c = (lane < cnt) ? col[eb + lane] : 0;
        int j = 0;
        for (; j + 4 <= cnt; j += 4) {
            int i0 = __shfl(c, j, 64), i1 = __shfl(c, j + 1, 64);
            int i2 = __shfl(c, j + 2, 64), i3 = __shfl(c, j + 3, 64);
            s0 += bfu2f(xin[((size_t)i0 << 6) + lane]);
            s1 += bfu2f(xin[((size_t)i1 << 6) + lane]);
            s2 += bfu2f(xin[((size_t)i2 << 6) + lane]);
            s3 += bfu2f(xin[((size_t)i3 << 6) + lane]);
        }
        for (; j < cnt; j++)
            s0 += bfu2f(xin[((size_t)__shfl(c, j, 64) << 6) + lane]);
    }
    float hv = (1.0f + *epsp) * bfu2f(xin[((size_t)node << 6) + lane]) +
               ((s0 + s1) + (s2 + s3));
    h[((size_t)node << 6) + lane] = f2bf(hv);
}

// ================= MFMA MLP + LN (+ fused gate on last layer) =================
// block = 4 waves = 64-node tile; each wave owns 16 nodes (M=16).
// Layouts (gfx950, 16x16x32 bf16): A[m=lane&15][k=quad*8+j]
//   B[k=quad*8+j][n=lane&15]   C/D col=lane&15, row=quad*4+reg
template <int LAST>
__global__ __launch_bounds__(256) void k_mfma(const unsigned short* __restrict__ h,
                                              unsigned short* __restrict__ xout,
                                              const float* __restrict__ W1,
                                              const float* __restrict__ b1,
                                              const float* __restrict__ W2,
                                              const float* __restrict__ b2,
                                              const float* __restrict__ lng,
                                              const float* __restrict__ lnb,
                                              const float* __restrict__ gw1,
                                              const float* __restrict__ gb1,
                                              const float* __restrict__ gw2,
                                              const float* __restrict__ gb2,
                                              float* __restrict__ gate) {
    __shared__ unsigned short a2[4][16 * 64];   // per-wave 16x64 bf16 staging
    int w = threadIdx.x >> 6;
    int lane = threadIdx.x & 63;
    int n = lane & 15;
    int q = lane >> 4;
    int base = blockIdx.x * 64 + w * 16;

    // ---- weight B-fragments (bf16, registers) ----
    short8 B1f[2][4], B2f[2][4];
#pragma unroll
    for (int ks = 0; ks < 2; ks++)
#pragma unroll
        for (int c = 0; c < 4; c++) {
            short8 f1, f2;
#pragma unroll
            for (int j = 0; j < 8; j++) {
                int k = ks * 32 + q * 8 + j;
                f1[j] = (short)f2bf(W1[k * 64 + c * 16 + n]);
                f2[j] = (short)f2bf(W2[k * 64 + c * 16 + n]);
            }
            B1f[ks][c] = f1;
            B2f[ks][c] = f2;
        }

    float b1v[4], b2v[4], lgv[4], lbv[4];
#pragma unroll
    for (int c = 0; c < 4; c++) {
        b1v[c] = b1[c * 16 + n];
        b2v[c] = b2[c * 16 + n];
        lgv[c] = lng[c * 16 + n];
        lbv[c] = lnb[c * 16 + n];
    }

    // ---- A fragments from h (direct bf16 16B loads) ----
    int mnode = base + n;
    int mc = min(mnode, NN - 1);
    const short8* hp = (const short8*)(h + ((size_t)mc << 6));
    short8 A0 = hp[q];
    short8 A1 = hp[4 + q];

    // ---- GEMM1: C1 = h @ W1 + b1 ----
    floatx4 acc1[4];
#pragma unroll
    for (int c = 0; c < 4; c++) {
        floatx4 a = {b1v[c], b1v[c], b1v[c], b1v[c]};
        a = __builtin_amdgcn_mfma_f32_16x16x32_bf16(A0, B1f[0][c], a, 0, 0, 0);
        a = __builtin_amdgcn_mfma_f32_16x16x32_bf16(A1, B1f[1][c], a, 0, 0, 0);
        acc1[c] = a;
    }

    // ---- silu -> LDS (C-layout -> A-layout round trip) ----
    unsigned short* aw = a2[w];
#pragma unroll
    for (int c = 0; c < 4; c++)
#pragma unroll
        for (int r = 0; r < 4; r++) {
            float v = acc1[c][r];
            v = v / (1.0f + __expf(-v));
            aw[(q * 4 + r) * 64 + c * 16 + n] = f2bf(v);
        }

    const short8* ap = (const short8*)(aw + n * 64);
    short8 A20 = ap[q];
    short8 A21 = ap[4 + q];

    // ---- GEMM2: C2 = silu(C1) @ W2 + b2 ----
    floatx4 acc2[4];
#pragma unroll
    for (int c = 0; c < 4; c++) {
        floatx4 a = {b2v[c], b2v[c], b2v[c], b2v[c]};
        a = __builtin_amdgcn_mfma_f32_16x16x32_bf16(A20, B2f[0][c], a, 0, 0, 0);
        a = __builtin_amdgcn_mfma_f32_16x16x32_bf16(A21, B2f[1][c], a, 0, 0, 0);
        acc2[c] = a;
    }

    // ---- LayerNorm across the 64 cols of each row ----
    float mu[4], inv[4];
#pragma unroll
    for (int r = 0; r < 4; r++) {
        float s = acc2[0][r] + acc2[1][r] + acc2[2][r] + acc2[3][r];
#pragma unroll
        for (int off = 1; off < 16; off <<= 1) s += __shfl_xor(s, off, 64);
        mu[r] = s * (1.0f / 64.0f);
        float d0 = acc2[0][r] - mu[r], d1 = acc2[1][r] - mu[r];
        float d2 = acc2[2][r] - mu[r], d3 = acc2[3][r] - mu[r];
        float vv = d0 * d0 + d1 * d1 + d2 * d2 + d3 * d3;
#pragma unroll
        for (int off = 1; off < 16; off <<= 1) vv += __shfl_xor(vv, off, 64);
        inv[r] = rsqrtf(vv * (1.0f / 64.0f) + LN_EPS);
    }

    // ---- store bf16 (+ stash for gate) ----
#pragma unroll
    for (int c = 0; c < 4; c++)
#pragma unroll
        for (int r = 0; r < 4; r++) {
            int node = base + q * 4 + r;
            float o = (acc2[c][r] - mu[r]) * inv[r] * lgv[c] + lbv[c];
            unsigned short ob = f2bf(o);
            if (node < NN) xout[((size_t)node << 6) + c * 16 + n] = ob;
            if (LAST) aw[(q * 4 + r) * 64 + c * 16 + n] = ob;
        }

    // ---- fused gate MLP (last layer) ----
    if (LAST) {
        short8 B3f[2][2];
#pragma unroll
        for (int ks = 0; ks < 2; ks++)
#pragma unroll
            for (int c = 0; c < 2; c++) {
                short8 f;
#pragma unroll
                for (int j = 0; j < 8; j++) {
                    int k = ks * 32 + q * 8 + j;
                    f[j] = (short)f2bf(gw1[k * 32 + c * 16 + n]);
                }
                B3f[ks][c] = f;
            }
        const short8* gp = (const short8*)(aw + n * 64);
        short8 G0 = gp[q];
        short8 G1 = gp[4 + q];
        floatx4 acc3[2];
#pragma unroll
        for (int c = 0; c < 2; c++) {
            float bv = gb1[c * 16 + n];
            floatx4 a = {bv, bv, bv, bv};
            a = __builtin_amdgcn_mfma_f32_16x16x32_bf16(G0, B3f[0][c], a, 0, 0, 0);
            a = __builtin_amdgcn_mfma_f32_16x16x32_bf16(G1, B3f[1][c], a, 0, 0, 0);
            acc3[c] = a;
        }
        float gw2v0 = gw2[n], gw2v1 = gw2[16 + n];
        float gb2v = gb2[0];
#pragma unroll
        for (int r = 0; r < 4; r++) {
            float v0 = acc3[0][r];
            v0 = v0 / (1.0f + __expf(-v0));
            float v1 = acc3[1][r];
            v1 = v1 / (1.0f + __expf(-v1));
            float gsum = v0 * gw2v0 + v1 * gw2v1;
#pragma unroll
            for (int off = 1; off < 16; off <<= 1) gsum += __shfl_xor(gsum, off, 64);
            int node = base + q * 4 + r;
            if (n == 0 && node < NN) gate[node] = gsum + gb2v;
        }
    }
}

// ================= per-graph softmax pooling (4 waves per graph, bf16 feats) =================
__global__ __launch_bounds__(256) void k_pool(const unsigned short* __restrict__ xf,
                                              const float* __restrict__ gate,
                                              const int* __restrict__ batch,
                                              float* __restrict__ out) {
    __shared__ float redm[4];
    __shared__ float reds[4];
    __shared__ float racc[4][D];
    int g = blockIdx.x;
    int w = threadIdx.x >> 6;
    int lane = threadIdx.x & 63;

    int lo = 0, hi = NN;
    while (lo < hi) { int mid = (lo + hi) >> 1; if (batch[mid] < g) lo = mid + 1; else hi = mid; }
    int start = lo;
    hi = NN;
    while (lo < hi) { int mid = (lo + hi) >> 1; if (batch[mid] < g + 1) lo = mid + 1; else hi = mid; }
    int end = lo;

    if (start >= end) {
        if (w == 0) out[((size_t)g << 6) + lane] = 0.0f;
        return;
    }

    float m = -INFINITY;
    for (int i = start + (int)threadIdx.x; i < end; i += 256) m = fmaxf(m, gate[i]);
#pragma unroll
    for (int mm = 32; mm >= 1; mm >>= 1) m = fmaxf(m, __shfl_xor(m, mm, 64));
    if (lane == 0) redm[w] = m;
    __syncthreads();
    m = fmaxf(fmaxf(redm[0], redm[1]), fmaxf(redm[2], redm[3]));

    float s = 0.0f;
    for (int i = start + (int)threadIdx.x; i < end; i += 256) s += __expf(gate[i] - m);
#pragma unroll
    for (int mm = 32; mm >= 1; mm >>= 1) s += __shfl_xor(s, mm, 64);
    if (lane == 0) reds[w] = s;
    __syncthreads();
    s = (reds[0] + reds[1]) + (reds[2] + reds[3]);

    float acc = 0.0f;
    for (int i = start + w; i < end; i += 4)
        acc += __expf(gate[i] - m) * bfu2f(xf[((size_t)i << 6) + lane]);
    racc[w][lane] = acc;
    __syncthreads();
    if (w == 0)
        out[((size_t)g << 6) + lane] =
            ((racc[0][lane] + racc[1][lane]) + (racc[2][lane] + racc[3][lane])) / s;
}

extern "C" void kernel_launch(void* const* d_in, const int* in_sizes, int n_in,
                              void* d_out, int out_size, void* d_ws, size_t ws_size,
                              hipStream_t stream) {
    const float* x   = (const float*)d_in[0];
    const int* ei    = (const int*)d_in[1];
    const int* batch = (const int*)d_in[2];
    const float* W1  = (const float*)d_in[3];
    const float* b1  = (const float*)d_in[4];
    const float* W2  = (const float*)d_in[5];
    const float* b2  = (const float*)d_in[6];
    const float* eps = (const float*)d_in[7];
    const float* lng = (const float*)d_in[8];
    const float* lnb = (const float*)d_in[9];
    const float* gw1 = (const float*)d_in[10];
    const float* gb1 = (const float*)d_in[11];
    const float* gw2 = (const float*)d_in[12];
    const float* gb2 = (const float*)d_in[13];

    const int* src = ei;
    const int* dst = ei + NE;

    // workspace layout (~40 MB)
    unsigned short* xb = (unsigned short*)d_ws;                // NN*64 bf16 (ping)
    unsigned short* h  = xb + (size_t)NN * D;                  // NN*64 bf16 (pong)
    float* gate        = (float*)(h + (size_t)NN * D);         // NN f32
    int* counts        = (int*)(gate + NN);                    // NN
    int* row_ptr       = counts + NN;                          // NN+1
    int* col           = row_ptr + NN + 1;                     // NE
    unsigned int* tmp  = (unsigned int*)(col + NE);            // NE
    int* bsum          = (int*)(tmp + NE);                     // NB
    int* bbase         = bsum + NB;                            // NB
    int* bcur          = bbase + NB;                           // NBK*16

    float* out = (float*)d_out;

    // ---- CSR build (bucketed two-phase fill) ----
    hipMemsetAsync(counts, 0, (size_t)NN * sizeof(int), stream);
    k_conv<<<(NN * D) / 256, 256, 0, stream>>>(x, xb);
    k_hist<<<NE / 256, 256, 0, stream>>>(dst, counts);
    k_bsum<<<NB, 256, 0, stream>>>(counts, bsum);
    k_bscan<<<1, 512, 0, stream>>>(bsum, bbase);
    k_apply<<<NB, 256, 0, stream>>>(counts, bbase, row_ptr);
    k_bcurinit<<<1, 512, 0, stream>>>(row_ptr, bcur);
    k_part<<<NE / 256, 256, 0, stream>>>(src, dst, bcur, tmp);
    k_bfill<<<NBK, 256, 0, stream>>>(tmp, row_ptr, col);

    // ---- 3 GIN layers: gather (bf16->bf16 h) then MFMA MLP ----
    k_gather<<<NN / 4, 256, 0, stream>>>(xb, h, row_ptr, col, eps + 0);
    k_mfma<0><<<NTILE, 256, 0, stream>>>(h, xb,
        W1 + 0 * D * D, b1 + 0 * D, W2 + 0 * D * D, b2 + 0 * D,
        lng + 0 * D, lnb + 0 * D, gw1, gb1, gw2, gb2, gate);

    k_gather<<<NN / 4, 256, 0, stream>>>(xb, h, row_ptr, col, eps + 1);
    k_mfma<0><<<NTILE, 256, 0, stream>>>(h, xb,
        W1 + 1 * D * D, b1 + 1 * D, W2 + 1 * D * D, b2 + 1 * D,
        lng + 1 * D, lnb + 1 * D, gw1, gb1, gw2, gb2, gate);

    k_gather<<<NN / 4, 256, 0, stream>>>(xb, h, row_ptr, col, eps + 2);
    k_mfma<1><<<NTILE, 256, 0, stream>>>(h, xb,
        W1 + 2 * D * D, b1 + 2 * D, W2 + 2 * D * D, b2 + 2 * D,
        lng + 2 * D, lnb + 2 * D, gw1, gb1, gw2, gb2, gate);

    k_pool<<<NG, 256, 0, stream>>>(xb, gate, batch, out);
}

// Round 8
// 424.489 us; speedup vs baseline: 11.0156x; 1.2004x over previous
//
#include <hip/hip_runtime.h>
#include <math.h>

#define NN 100000
#define NE 1600000
#define D 64
#define NG 2000
#define LN_EPS 1e-5f
#define NB ((NN + 255) / 256)        // 391 (scan blocks == buckets)
#define NBK NB                       // buckets of 256 nodes
#define NTILE ((NN + 63) / 64)       // 1563
#define EPB 6400                     // edges per partition block (250 blocks)

typedef __attribute__((ext_vector_type(8))) short short8;   // 8 bf16 in 4 VGPRs
typedef __attribute__((ext_vector_type(4))) float floatx4;  // MFMA accumulator

__device__ __forceinline__ unsigned short f2bf(float f) {
    unsigned int u = __float_as_uint(f);
    u += 0x7FFF + ((u >> 16) & 1);   // round-to-nearest-even
    return (unsigned short)(u >> 16);
}
__device__ __forceinline__ float bfu2f(unsigned short v) {
    return __uint_as_float(((unsigned int)v) << 16);
}

// ================= fp32 -> bf16 feature convert =================
__global__ __launch_bounds__(256) void k_conv(const float* __restrict__ x,
                                              unsigned short* __restrict__ xb) {
    int i = blockIdx.x * 256 + threadIdx.x;
    xb[i] = f2bf(x[i]);
}

// ================= CSR build =================
__global__ __launch_bounds__(256) void k_hist(const int* __restrict__ dst,
                                              int* __restrict__ counts) {
    int e = blockIdx.x * 256 + threadIdx.x;
    atomicAdd(&counts[dst[e]], 1);
}

__global__ __launch_bounds__(256) void k_bsum(const int* __restrict__ counts,
                                              int* __restrict__ bsum) {
    __shared__ int red[4];
    int i = blockIdx.x * 256 + threadIdx.x;
    int v = (i < NN) ? counts[i] : 0;
#pragma unroll
    for (int m = 32; m >= 1; m >>= 1) v += __shfl_xor(v, m, 64);
    if ((threadIdx.x & 63) == 0) red[threadIdx.x >> 6] = v;
    __syncthreads();
    if (threadIdx.x == 0) bsum[blockIdx.x] = red[0] + red[1] + red[2] + red[3];
}

__global__ __launch_bounds__(512) void k_bscan(const int* __restrict__ bsum,
                                               int* __restrict__ bbase) {
    __shared__ int s[512];
    int t = threadIdx.x;
    int v = (t < NB) ? bsum[t] : 0;
    s[t] = v;
    __syncthreads();
    for (int off = 1; off < 512; off <<= 1) {
        int u = (t >= off) ? s[t - off] : 0;
        __syncthreads();
        s[t] += u;
        __syncthreads();
    }
    if (t < NB) bbase[t] = s[t] - v;
}

__global__ __launch_bounds__(256) void k_apply(const int* __restrict__ counts,
                                               const int* __restrict__ bbase,
                                               int* __restrict__ row_ptr) {
    __shared__ int wsum[4];
    int i = blockIdx.x * 256 + threadIdx.x;
    int lane = threadIdx.x & 63;
    int w = threadIdx.x >> 6;
    int v = (i < NN) ? counts[i] : 0;
    int x = v;
#pragma unroll
    for (int off = 1; off < 64; off <<= 1) {
        int u = __shfl_up(x, off, 64);
        if (lane >= off) x += u;
    }
    if (lane == 63) wsum[w] = x;
    __syncthreads();
    int base = bbase[blockIdx.x];
    for (int k = 0; k < w; k++) base += wsum[k];
    if (i < NN) row_ptr[i] = base + x - v;
    if (i == 0) row_ptr[NN] = NE;
}

// bucket cursors: one per 64B line to avoid same-line atomic serialization
__global__ __launch_bounds__(512) void k_bcurinit(const int* __restrict__ row_ptr,
                                                  int* __restrict__ bcur) {
    int b = threadIdx.x;
    if (b < NBK) bcur[b * 16] = row_ptr[b * 256];
}

// phase B: block-local two-pass partition into bucket-major tmp.
// Each block reserves contiguous per-bucket segments -> each tmp line is
// written by ~1 block -> full lines accumulate in one L2 before writeback.
__global__ __launch_bounds__(256) void k_part(const int* __restrict__ src,
                                              const int* __restrict__ dst,
                                              int* __restrict__ bcur,
                                              unsigned int* __restrict__ tmp) {
    __shared__ int lcnt[NBK];
    __shared__ int lbase[NBK];
    int e0 = blockIdx.x * EPB;
    int tid = threadIdx.x;

    for (int i = tid; i < NBK; i += 256) lcnt[i] = 0;
    __syncthreads();

    // pass 1: per-bucket counts for this chunk
    for (int k = 0; k < EPB; k += 256) {
        int d = dst[e0 + k + tid];
        atomicAdd(&lcnt[d >> 8], 1);
    }
    __syncthreads();

    // reserve contiguous global segments
    for (int i = tid; i < NBK; i += 256) {
        int c = lcnt[i];
        lbase[i] = c ? atomicAdd(&bcur[i * 16], c) : 0;
        lcnt[i] = 0;
    }
    __syncthreads();

    // pass 2: write into block-owned segments
    for (int k = 0; k < EPB; k += 256) {
        int e = e0 + k + tid;
        int d = dst[e];
        int s = src[e];
        int b = d >> 8;
        int pos = lbase[b] + atomicAdd(&lcnt[b], 1);
        tmp[pos] = ((unsigned int)s << 8) | (unsigned int)(d & 255);
    }
}

// phase C: per-bucket fill; scatter confined to ~16KB col window (cache-resident)
__global__ __launch_bounds__(256) void k_bfill(const unsigned int* __restrict__ tmp,
                                               const int* __restrict__ row_ptr,
                                               int* __restrict__ col) {
    __shared__ int lcur[256];
    int b = blockIdx.x;
    int nb0 = b * 256;
    int nend = min(nb0 + 256, NN);
    int cnt = nend - nb0;
    int tid = threadIdx.x;
    if (tid < cnt) lcur[tid] = row_ptr[nb0 + tid];
    __syncthreads();
    int estart = row_ptr[nb0];
    int eend = row_ptr[nend];
    for (int e = estart + tid; e < eend; e += 256) {
        unsigned int p = tmp[e];
        int pos = atomicAdd(&lcur[p & 255], 1);
        col[pos] = (int)(p >> 8);
    }
}

// ================= gather: h = (1+eps)x + sum_neighbors (bf16 in/out) =================
// 4 nodes per wave: 16-lane group per node, each lane owns 4 features (8B loads)
__global__ __launch_bounds__(256) void k_gather(const unsigned short* __restrict__ xin,
                                                unsigned short* __restrict__ h,
                                                const int* __restrict__ row_ptr,
                                                const int* __restrict__ col,
                                                const float* __restrict__ epsp) {
    int w = threadIdx.x >> 6;
    int lane = threadIdx.x & 63;
    int g = lane >> 4;        // group within wave
    int fl = lane & 15;       // feature-lane: features fl*4..fl*4+3
    int node = (blockIdx.x * 4 + w) * 4 + g;
    int start = row_ptr[node], end = row_ptr[node + 1];

    float a0 = 0.f, a1 = 0.f, a2 = 0.f, a3 = 0.f;
    for (int eb = start; eb < end; eb += 16) {
        int cnt = min(16, end - eb);
        int c = (fl < cnt) ? col[eb + fl] : 0;
        for (int j = 0; j < cnt; j++) {
            int idx = __shfl(c, g * 16 + j, 64);
            ushort4 v = *(const ushort4*)(xin + ((size_t)idx << 6) + fl * 4);
            a0 += bfu2f(v.x);
            a1 += bfu2f(v.y);
            a2 += bfu2f(v.z);
            a3 += bfu2f(v.w);
        }
    }
    float ev = 1.0f + *epsp;
    ushort4 xs = *(const ushort4*)(xin + ((size_t)node << 6) + fl * 4);
    ushort4 o;
    o.x = f2bf(ev * bfu2f(xs.x) + a0);
    o.y = f2bf(ev * bfu2f(xs.y) + a1);
    o.z = f2bf(ev * bfu2f(xs.z) + a2);
    o.w = f2bf(ev * bfu2f(xs.w) + a3);
    *(ushort4*)(h + ((size_t)node << 6) + fl * 4) = o;
}

// ================= MFMA MLP + LN (+ fused gate on last layer) =================
// block = 4 waves = 64-node tile; each wave owns 16 nodes (M=16).
// Layouts (gfx950, 16x16x32 bf16): A[m=lane&15][k=quad*8+j]
//   B[k=quad*8+j][n=lane&15]   C/D col=lane&15, row=quad*4+reg
template <int LAST>
__global__ __launch_bounds__(256) void k_mfma(const unsigned short* __restrict__ h,
                                              unsigned short* __restrict__ xout,
                                              const float* __restrict__ W1,
                                              const float* __restrict__ b1,
                                              const float* __restrict__ W2,
                                              const float* __restrict__ b2,
                                              const float* __restrict__ lng,
                                              const float* __restrict__ lnb,
                                              const float* __restrict__ gw1,
                                              const float* __restrict__ gb1,
                                              const float* __restrict__ gw2,
                                              const float* __restrict__ gb2,
                                              float* __restrict__ gate) {
    __shared__ unsigned short a2[4][16 * 64];   // per-wave 16x64 bf16 staging
    int w = threadIdx.x >> 6;
    int lane = threadIdx.x & 63;
    int n = lane & 15;
    int q = lane >> 4;
    int base = blockIdx.x * 64 + w * 16;

    // ---- weight B-fragments (bf16, registers) ----
    short8 B1f[2][4], B2f[2][4];
#pragma unroll
    for (int ks = 0; ks < 2; ks++)
#pragma unroll
        for (int c = 0; c < 4; c++) {
            short8 f1, f2;
#pragma unroll
            for (int j = 0; j < 8; j++) {
                int k = ks * 32 + q * 8 + j;
                f1[j] = (short)f2bf(W1[k * 64 + c * 16 + n]);
                f2[j] = (short)f2bf(W2[k * 64 + c * 16 + n]);
            }
            B1f[ks][c] = f1;
            B2f[ks][c] = f2;
        }

    float b1v[4], b2v[4], lgv[4], lbv[4];
#pragma unroll
    for (int c = 0; c < 4; c++) {
        b1v[c] = b1[c * 16 + n];
        b2v[c] = b2[c * 16 + n];
        lgv[c] = lng[c * 16 + n];
        lbv[c] = lnb[c * 16 + n];
    }

    // ---- A fragments from h (direct bf16 16B loads) ----
    int mnode = base + n;
    int mc = min(mnode, NN - 1);
    const short8* hp = (const short8*)(h + ((size_t)mc << 6));
    short8 A0 = hp[q];
    short8 A1 = hp[4 + q];

    // ---- GEMM1: C1 = h @ W1 + b1 ----
    floatx4 acc1[4];
#pragma unroll
    for (int c = 0; c < 4; c++) {
        floatx4 a = {b1v[c], b1v[c], b1v[c], b1v[c]};
        a = __builtin_amdgcn_mfma_f32_16x16x32_bf16(A0, B1f[0][c], a, 0, 0, 0);
        a = __builtin_amdgcn_mfma_f32_16x16x32_bf16(A1, B1f[1][c], a, 0, 0, 0);
        acc1[c] = a;
    }

    // ---- silu -> LDS (C-layout -> A-layout round trip) ----
    unsigned short* aw = a2[w];
#pragma unroll
    for (int c = 0; c < 4; c++)
#pragma unroll
        for (int r = 0; r < 4; r++) {
            float v = acc1[c][r];
            v = v / (1.0f + __expf(-v));
            aw[(q * 4 + r) * 64 + c * 16 + n] = f2bf(v);
        }

    const short8* ap = (const short8*)(aw + n * 64);
    short8 A20 = ap[q];
    short8 A21 = ap[4 + q];

    // ---- GEMM2: C2 = silu(C1) @ W2 + b2 ----
    floatx4 acc2[4];
#pragma unroll
    for (int c = 0; c < 4; c++) {
        floatx4 a = {b2v[c], b2v[c], b2v[c], b2v[c]};
        a = __builtin_amdgcn_mfma_f32_16x16x32_bf16(A20, B2f[0][c], a, 0, 0, 0);
        a = __builtin_amdgcn_mfma_f32_16x16x32_bf16(A21, B2f[1][c], a, 0, 0, 0);
        acc2[c] = a;
    }

    // ---- LayerNorm across the 64 cols of each row ----
    float mu[4], inv[4];
#pragma unroll
    for (int r = 0; r < 4; r++) {
        float s = acc2[0][r] + acc2[1][r] + acc2[2][r] + acc2[3][r];
#pragma unroll
        for (int off = 1; off < 16; off <<= 1) s += __shfl_xor(s, off, 64);
        mu[r] = s * (1.0f / 64.0f);
        float d0 = acc2[0][r] - mu[r], d1 = acc2[1][r] - mu[r];
        float d2 = acc2[2][r] - mu[r], d3 = acc2[3][r] - mu[r];
        float vv = d0 * d0 + d1 * d1 + d2 * d2 + d3 * d3;
#pragma unroll
        for (int off = 1; off < 16; off <<= 1) vv += __shfl_xor(vv, off, 64);
        inv[r] = rsqrtf(vv * (1.0f / 64.0f) + LN_EPS);
    }

    // ---- store bf16 (+ stash for gate) ----
#pragma unroll
    for (int c = 0; c < 4; c++)
#pragma unroll
        for (int r = 0; r < 4; r++) {
            int node = base + q * 4 + r;
            float o = (acc2[c][r] - mu[r]) * inv[r] * lgv[c] + lbv[c];
            unsigned short ob = f2bf(o);
            if (node < NN) xout[((size_t)node << 6) + c * 16 + n] = ob;
            if (LAST) aw[(q * 4 + r) * 64 + c * 16 + n] = ob;
        }

    // ---- fused gate MLP (last layer) ----
    if (LAST) {
        short8 B3f[2][2];
#pragma unroll
        for (int ks = 0; ks < 2; ks++)
#pragma unroll
            for (int c = 0; c < 2; c++) {
                short8 f;
#pragma unroll
                for (int j = 0; j < 8; j++) {
                    int k = ks * 32 + q * 8 + j;
                    f[j] = (short)f2bf(gw1[k * 32 + c * 16 + n]);
                }
                B3f[ks][c] = f;
            }
        const short8* gp = (const short8*)(aw + n * 64);
        short8 G0 = gp[q];
        short8 G1 = gp[4 + q];
        floatx4 acc3[2];
#pragma unroll
        for (int c = 0; c < 2; c++) {
            float bv = gb1[c * 16 + n];
            floatx4 a = {bv, bv, bv, bv};
            a = __builtin_amdgcn_mfma_f32_16x16x32_bf16(G0, B3f[0][c], a, 0, 0, 0);
            a = __builtin_amdgcn_mfma_f32_16x16x32_bf16(G1, B3f[1][c], a, 0, 0, 0);
            acc3[c] = a;
        }
        float gw2v0 = gw2[n], gw2v1 = gw2[16 + n];
        float gb2v = gb2[0];
#pragma unroll
        for (int r = 0; r < 4; r++) {
            float v0 = acc3[0][r];
            v0 = v0 / (1.0f + __expf(-v0));
            float v1 = acc3[1][r];
            v1 = v1 / (1.0f + __expf(-v1));
            float gsum = v0 * gw2v0 + v1 * gw2v1;
#pragma unroll
            for (int off = 1; off < 16; off <<= 1) gsum += __shfl_xor(gsum, off, 64);
            int node = base + q * 4 + r;
            if (n == 0 && node < NN) gate[node] = gsum + gb2v;
        }
    }
}

// ================= per-graph softmax pooling (4 waves per graph, bf16 feats) =================
__global__ __launch_bounds__(256) void k_pool(const unsigned short* __restrict__ xf,
                                              const float* __restrict__ gate,
                                              const int* __restrict__ batch,
                                              float* __restrict__ out) {
    __shared__ float redm[4];
    __shared__ float reds[4];
    __shared__ float racc[4][D];
    int g = blockIdx.x;
    int w = threadIdx.x >> 6;
    int lane = threadIdx.x & 63;

    int lo = 0, hi = NN;
    while (lo < hi) { int mid = (lo + hi) >> 1; if (batch[mid] < g) lo = mid + 1; else hi = mid; }
    int start = lo;
    hi = NN;
    while (lo < hi) { int mid = (lo + hi) >> 1; if (batch[mid] < g + 1) lo = mid + 1; else hi = mid; }
    int end = lo;

    if (start >= end) {
        if (w == 0) out[((size_t)g << 6) + lane] = 0.0f;
        return;
    }

    float m = -INFINITY;
    for (int i = start + (int)threadIdx.x; i < end; i += 256) m = fmaxf(m, gate[i]);
#pragma unroll
    for (int mm = 32; mm >= 1; mm >>= 1) m = fmaxf(m, __shfl_xor(m, mm, 64));
    if (lane == 0) redm[w] = m;
    __syncthreads();
    m = fmaxf(fmaxf(redm[0], redm[1]), fmaxf(redm[2], redm[3]));

    float s = 0.0f;
    for (int i = start + (int)threadIdx.x; i < end; i += 256) s += __expf(gate[i] - m);
#pragma unroll
    for (int mm = 32; mm >= 1; mm >>= 1) s += __shfl_xor(s, mm, 64);
    if (lane == 0) reds[w] = s;
    __syncthreads();
    s = (reds[0] + reds[1]) + (reds[2] + reds[3]);

    float acc = 0.0f;
    for (int i = start + w; i < end; i += 4)
        acc += __expf(gate[i] - m) * bfu2f(xf[((size_t)i << 6) + lane]);
    racc[w][lane] = acc;
    __syncthreads();
    if (w == 0)
        out[((size_t)g << 6) + lane] =
            ((racc[0][lane] + racc[1][lane]) + (racc[2][lane] + racc[3][lane])) / s;
}

extern "C" void kernel_launch(void* const* d_in, const int* in_sizes, int n_in,
                              void* d_out, int out_size, void* d_ws, size_t ws_size,
                              hipStream_t stream) {
    const float* x   = (const float*)d_in[0];
    const int* ei    = (const int*)d_in[1];
    const int* batch = (const int*)d_in[2];
    const float* W1  = (const float*)d_in[3];
    const float* b1  = (const float*)d_in[4];
    const float* W2  = (const float*)d_in[5];
    const float* b2  = (const float*)d_in[6];
    const float* eps = (const float*)d_in[7];
    const float* lng = (const float*)d_in[8];
    const float* lnb = (const float*)d_in[9];
    const float* gw1 = (const float*)d_in[10];
    const float* gb1 = (const float*)d_in[11];
    const float* gw2 = (const float*)d_in[12];
    const float* gb2 = (const float*)d_in[13];

    const int* src = ei;
    const int* dst = ei + NE;

    // workspace layout (~40 MB)
    unsigned short* xb = (unsigned short*)d_ws;                // NN*64 bf16 (ping)
    unsigned short* h  = xb + (size_t)NN * D;                  // NN*64 bf16 (pong)
    float* gate        = (float*)(h + (size_t)NN * D);         // NN f32
    int* counts        = (int*)(gate + NN);                    // NN
    int* row_ptr       = counts + NN;                          // NN+1
    int* col           = row_ptr + NN + 1;                     // NE
    unsigned int* tmp  = (unsigned int*)(col + NE);            // NE
    int* bsum          = (int*)(tmp + NE);                     // NB
    int* bbase         = bsum + NB;                            // NB
    int* bcur          = bbase + NB;                           // NBK*16

    float* out = (float*)d_out;

    // ---- CSR build (bucketed two-phase fill) ----
    hipMemsetAsync(counts, 0, (size_t)NN * sizeof(int), stream);
    k_conv<<<(NN * D) / 256, 256, 0, stream>>>(x, xb);
    k_hist<<<NE / 256, 256, 0, stream>>>(dst, counts);
    k_bsum<<<NB, 256, 0, stream>>>(counts, bsum);
    k_bscan<<<1, 512, 0, stream>>>(bsum, bbase);
    k_apply<<<NB, 256, 0, stream>>>(counts, bbase, row_ptr);
    k_bcurinit<<<1, 512, 0, stream>>>(row_ptr, bcur);
    k_part<<<NE / EPB, 256, 0, stream>>>(src, dst, bcur, tmp);
    k_bfill<<<NBK, 256, 0, stream>>>(tmp, row_ptr, col);

    // ---- 3 GIN layers: gather (bf16->bf16 h) then MFMA MLP ----
    k_gather<<<NN / 16, 256, 0, stream>>>(xb, h, row_ptr, col, eps + 0);
    k_mfma<0><<<NTILE, 256, 0, stream>>>(h, xb,
        W1 + 0 * D * D, b1 + 0 * D, W2 + 0 * D * D, b2 + 0 * D,
        lng + 0 * D, lnb + 0 * D, gw1, gb1, gw2, gb2, gate);

    k_gather<<<NN / 16, 256, 0, stream>>>(xb, h, row_ptr, col, eps + 1);
    k_mfma<0><<<NTILE, 256, 0, stream>>>(h, xb,
        W1 + 1 * D * D, b1 + 1 * D, W2 + 1 * D * D, b2 + 1 * D,
        lng + 1 * D, lnb + 1 * D, gw1, gb1, gw2, gb2, gate);

    k_gather<<<NN / 16, 256, 0, stream>>>(xb, h, row_ptr, col, eps + 2);
    k_mfma<1><<<NTILE, 256, 0, stream>>>(h, xb,
        W1 + 2 * D * D, b1 + 2 * D, W2 + 2 * D * D, b2 + 2 * D,
        lng + 2 * D, lnb + 2 * D, gw1, gb1, gw2, gb2, gate);

    k_pool<<<NG, 256, 0, stream>>>(xb, gate, batch, out);
}

// Round 9
// 341.347 us; speedup vs baseline: 13.6986x; 1.2436x over previous
//
#include <hip/hip_runtime.h>
#include <math.h>

#define NN 100000
#define NE 1600000
#define D 64
#define NG 2000
#define LN_EPS 1e-5f
#define NB ((NN + 255) / 256)        // 391 buckets of 256 nodes
#define NBK NB
#define NTILE ((NN + 63) / 64)       // 1563
#define EPB 6400                     // edges per partition block (250 blocks)

typedef __attribute__((ext_vector_type(8))) short short8;   // 8 bf16 in 4 VGPRs
typedef __attribute__((ext_vector_type(4))) float floatx4;  // MFMA accumulator

__device__ __forceinline__ unsigned short f2bf(float f) {
    unsigned int u = __float_as_uint(f);
    u += 0x7FFF + ((u >> 16) & 1);   // round-to-nearest-even
    return (unsigned short)(u >> 16);
}
__device__ __forceinline__ float bfu2f(unsigned short v) {
    return __uint_as_float(((unsigned int)v) << 16);
}

// ================= fp32 -> bf16 feature convert =================
__global__ __launch_bounds__(256) void k_conv(const float* __restrict__ x,
                                              unsigned short* __restrict__ xb) {
    int i = blockIdx.x * 256 + threadIdx.x;
    xb[i] = f2bf(x[i]);
}

// ================= bucket totals (LDS histogram, ~98K global atomics) =================
__global__ __launch_bounds__(256) void k_bcount(const int* __restrict__ dst,
                                                int* __restrict__ btot) {
    __shared__ int lcnt[NBK];
    int e0 = blockIdx.x * EPB;
    int tid = threadIdx.x;
    for (int i = tid; i < NBK; i += 256) lcnt[i] = 0;
    __syncthreads();
    for (int k = 0; k < EPB; k += 256)
        atomicAdd(&lcnt[dst[e0 + k + tid] >> 8], 1);
    __syncthreads();
    for (int i = tid; i < NBK; i += 256) {
        int c = lcnt[i];
        if (c) atomicAdd(&btot[i], c);
    }
}

// ================= scan 391 bucket totals -> bbase[NB+1] =================
__global__ __launch_bounds__(512) void k_bscan(const int* __restrict__ btot,
                                               int* __restrict__ bbase) {
    __shared__ int s[512];
    int t = threadIdx.x;
    int v = (t < NB) ? btot[t] : 0;
    s[t] = v;
    __syncthreads();
    for (int off = 1; off < 512; off <<= 1) {
        int u = (t >= off) ? s[t - off] : 0;
        __syncthreads();
        s[t] += u;
        __syncthreads();
    }
    if (t < NB) bbase[t] = s[t] - v;
    if (t == NB - 1) bbase[NB] = s[t];
}

// bucket cursors (one per 64B line) + row_ptr sentinel
__global__ __launch_bounds__(512) void k_bcurinit(const int* __restrict__ bbase,
                                                  int* __restrict__ bcur,
                                                  int* __restrict__ row_ptr) {
    int b = threadIdx.x;
    if (b < NBK) bcur[b * 16] = bbase[b];
    if (b == 0) row_ptr[NN] = NE;
}

// phase B: block-local two-pass partition into bucket-major tmp.
// Chunk cached in LDS so dst/src are read from HBM exactly once.
__global__ __launch_bounds__(256) void k_part(const int* __restrict__ src,
                                              const int* __restrict__ dst,
                                              int* __restrict__ bcur,
                                              unsigned int* __restrict__ tmp) {
    __shared__ int lcnt[NBK];
    __shared__ int lbase[NBK];
    __shared__ int sd[EPB];
    __shared__ int ss[EPB];
    int e0 = blockIdx.x * EPB;
    int tid = threadIdx.x;

    for (int i = tid; i < NBK; i += 256) lcnt[i] = 0;
    __syncthreads();

    // pass 1: stash chunk + per-bucket counts
    for (int k = 0; k < EPB; k += 256) {
        int d = dst[e0 + k + tid];
        int s = src[e0 + k + tid];
        sd[k + tid] = d;
        ss[k + tid] = s;
        atomicAdd(&lcnt[d >> 8], 1);
    }
    __syncthreads();

    // reserve contiguous global segments
    for (int i = tid; i < NBK; i += 256) {
        int c = lcnt[i];
        lbase[i] = c ? atomicAdd(&bcur[i * 16], c) : 0;
        lcnt[i] = 0;
    }
    __syncthreads();

    // pass 2: write into block-owned segments (from LDS)
    for (int k = 0; k < EPB; k += 256) {
        int d = sd[k + tid];
        int s = ss[k + tid];
        int b = d >> 8;
        int pos = lbase[b] + atomicAdd(&lcnt[b], 1);
        tmp[pos] = ((unsigned int)s << 8) | (unsigned int)(d & 255);
    }
}

// phase C: per-bucket node histogram + scan -> row_ptr, then col fill.
// All scatter confined to the bucket's ~16KB window (cache-resident).
__global__ __launch_bounds__(256) void k_bfill(const unsigned int* __restrict__ tmp,
                                               const int* __restrict__ bbase,
                                               int* __restrict__ row_ptr,
                                               int* __restrict__ col) {
    __shared__ int lcur[256];
    __shared__ int wsum[4];
    int b = blockIdx.x;
    int nb0 = b * 256;
    int nodes = min(256, NN - nb0);
    int tid = threadIdx.x;
    int lane = tid & 63;
    int w = tid >> 6;
    int estart = bbase[b], eend = bbase[b + 1];

    // node histogram within bucket
    lcur[tid] = 0;
    __syncthreads();
    for (int e = estart + tid; e < eend; e += 256)
        atomicAdd(&lcur[tmp[e] & 255], 1);
    __syncthreads();

    // block exclusive scan of 256 counts
    int v = lcur[tid];
    int x = v;
#pragma unroll
    for (int off = 1; off < 64; off <<= 1) {
        int u = __shfl_up(x, off, 64);
        if (lane >= off) x += u;
    }
    if (lane == 63) wsum[w] = x;
    __syncthreads();
    int base = estart;
    for (int k = 0; k < w; k++) base += wsum[k];
    int rp = base + x - v;   // global CSR start for node nb0+tid
    if (tid < nodes) row_ptr[nb0 + tid] = rp;
    lcur[tid] = rp;
    __syncthreads();

    // scatter col within window
    for (int e = estart + tid; e < eend; e += 256) {
        unsigned int p = tmp[e];
        int pos = atomicAdd(&lcur[p & 255], 1);
        col[pos] = (int)(p >> 8);
    }
}

// ================= gather: h = (1+eps)x + sum_neighbors (bf16 in/out) =================
// 4 nodes per wave: 16-lane group per node, lane owns 4 feats; 4 load streams
__global__ __launch_bounds__(256) void k_gather(const unsigned short* __restrict__ xin,
                                                unsigned short* __restrict__ h,
                                                const int* __restrict__ row_ptr,
                                                const int* __restrict__ col,
                                                const float* __restrict__ epsp) {
    int w = threadIdx.x >> 6;
    int lane = threadIdx.x & 63;
    int g = lane >> 4;
    int fl = lane & 15;
    int node = (blockIdx.x * 4 + w) * 4 + g;
    int start = row_ptr[node], end = row_ptr[node + 1];

    float4 A0 = {0, 0, 0, 0}, A1 = {0, 0, 0, 0}, A2 = {0, 0, 0, 0}, A3 = {0, 0, 0, 0};
    for (int eb = start; eb < end; eb += 16) {
        int cnt = min(16, end - eb);
        int c = (fl < cnt) ? col[eb + fl] : 0;
        int j = 0;
        for (; j + 4 <= cnt; j += 4) {
            int i0 = __shfl(c, g * 16 + j, 64);
            int i1 = __shfl(c, g * 16 + j + 1, 64);
            int i2 = __shfl(c, g * 16 + j + 2, 64);
            int i3 = __shfl(c, g * 16 + j + 3, 64);
            ushort4 v0 = *(const ushort4*)(xin + ((size_t)i0 << 6) + fl * 4);
            ushort4 v1 = *(const ushort4*)(xin + ((size_t)i1 << 6) + fl * 4);
            ushort4 v2 = *(const ushort4*)(xin + ((size_t)i2 << 6) + fl * 4);
            ushort4 v3 = *(const ushort4*)(xin + ((size_t)i3 << 6) + fl * 4);
            A0.x += bfu2f(v0.x); A0.y += bfu2f(v0.y); A0.z += bfu2f(v0.z); A0.w += bfu2f(v0.w);
            A1.x += bfu2f(v1.x); A1.y += bfu2f(v1.y); A1.z += bfu2f(v1.z); A1.w += bfu2f(v1.w);
            A2.x += bfu2f(v2.x); A2.y += bfu2f(v2.y); A2.z += bfu2f(v2.z); A2.w += bfu2f(v2.w);
            A3.x += bfu2f(v3.x); A3.y += bfu2f(v3.y); A3.z += bfu2f(v3.z); A3.w += bfu2f(v3.w);
        }
        for (; j < cnt; j++) {
            int i0 = __shfl(c, g * 16 + j, 64);
            ushort4 v0 = *(const ushort4*)(xin + ((size_t)i0 << 6) + fl * 4);
            A0.x += bfu2f(v0.x); A0.y += bfu2f(v0.y); A0.z += bfu2f(v0.z); A0.w += bfu2f(v0.w);
        }
    }
    float ev = 1.0f + *epsp;
    ushort4 xs = *(const ushort4*)(xin + ((size_t)node << 6) + fl * 4);
    ushort4 o;
    o.x = f2bf(ev * bfu2f(xs.x) + ((A0.x + A1.x) + (A2.x + A3.x)));
    o.y = f2bf(ev * bfu2f(xs.y) + ((A0.y + A1.y) + (A2.y + A3.y)));
    o.z = f2bf(ev * bfu2f(xs.z) + ((A0.z + A1.z) + (A2.z + A3.z)));
    o.w = f2bf(ev * bfu2f(xs.w) + ((A0.w + A1.w) + (A2.w + A3.w)));
    *(ushort4*)(h + ((size_t)node << 6) + fl * 4) = o;
}

// ================= MFMA MLP + LN (+ fused gate on last layer) =================
// block = 4 waves = 64-node tile; each wave owns 16 nodes (M=16).
// Layouts (gfx950, 16x16x32 bf16): A[m=lane&15][k=quad*8+j]
//   B[k=quad*8+j][n=lane&15]   C/D col=lane&15, row=quad*4+reg
template <int LAST>
__global__ __launch_bounds__(256) void k_mfma(const unsigned short* __restrict__ h,
                                              unsigned short* __restrict__ xout,
                                              const float* __restrict__ W1,
                                              const float* __restrict__ b1,
                                              const float* __restrict__ W2,
                                              const float* __restrict__ b2,
                                              const float* __restrict__ lng,
                                              const float* __restrict__ lnb,
                                              const float* __restrict__ gw1,
                                              const float* __restrict__ gb1,
                                              const float* __restrict__ gw2,
                                              const float* __restrict__ gb2,
                                              float* __restrict__ gate) {
    __shared__ unsigned short a2[4][16 * 64];   // per-wave 16x64 bf16 staging
    int w = threadIdx.x >> 6;
    int lane = threadIdx.x & 63;
    int n = lane & 15;
    int q = lane >> 4;
    int base = blockIdx.x * 64 + w * 16;

    // ---- weight B-fragments (bf16, registers) ----
    short8 B1f[2][4], B2f[2][4];
#pragma unroll
    for (int ks = 0; ks < 2; ks++)
#pragma unroll
        for (int c = 0; c < 4; c++) {
            short8 f1, f2;
#pragma unroll
            for (int j = 0; j < 8; j++) {
                int k = ks * 32 + q * 8 + j;
                f1[j] = (short)f2bf(W1[k * 64 + c * 16 + n]);
                f2[j] = (short)f2bf(W2[k * 64 + c * 16 + n]);
            }
            B1f[ks][c] = f1;
            B2f[ks][c] = f2;
        }

    float b1v[4], b2v[4], lgv[4], lbv[4];
#pragma unroll
    for (int c = 0; c < 4; c++) {
        b1v[c] = b1[c * 16 + n];
        b2v[c] = b2[c * 16 + n];
        lgv[c] = lng[c * 16 + n];
        lbv[c] = lnb[c * 16 + n];
    }

    // ---- A fragments from h (direct bf16 16B loads) ----
    int mnode = base + n;
    int mc = min(mnode, NN - 1);
    const short8* hp = (const short8*)(h + ((size_t)mc << 6));
    short8 A0 = hp[q];
    short8 A1 = hp[4 + q];

    // ---- GEMM1: C1 = h @ W1 + b1 ----
    floatx4 acc1[4];
#pragma unroll
    for (int c = 0; c < 4; c++) {
        floatx4 a = {b1v[c], b1v[c], b1v[c], b1v[c]};
        a = __builtin_amdgcn_mfma_f32_16x16x32_bf16(A0, B1f[0][c], a, 0, 0, 0);
        a = __builtin_amdgcn_mfma_f32_16x16x32_bf16(A1, B1f[1][c], a, 0, 0, 0);
        acc1[c] = a;
    }

    // ---- silu -> LDS (C-layout -> A-layout round trip) ----
    unsigned short* aw = a2[w];
#pragma unroll
    for (int c = 0; c < 4; c++)
#pragma unroll
        for (int r = 0; r < 4; r++) {
            float v = acc1[c][r];
            v = v / (1.0f + __expf(-v));
            aw[(q * 4 + r) * 64 + c * 16 + n] = f2bf(v);
        }

    const short8* ap = (const short8*)(aw + n * 64);
    short8 A20 = ap[q];
    short8 A21 = ap[4 + q];

    // ---- GEMM2: C2 = silu(C1) @ W2 + b2 ----
    floatx4 acc2[4];
#pragma unroll
    for (int c = 0; c < 4; c++) {
        floatx4 a = {b2v[c], b2v[c], b2v[c], b2v[c]};
        a = __builtin_amdgcn_mfma_f32_16x16x32_bf16(A20, B2f[0][c], a, 0, 0, 0);
        a = __builtin_amdgcn_mfma_f32_16x16x32_bf16(A21, B2f[1][c], a, 0, 0, 0);
        acc2[c] = a;
    }

    // ---- LayerNorm across the 64 cols of each row ----
    float mu[4], inv[4];
#pragma unroll
    for (int r = 0; r < 4; r++) {
        float s = acc2[0][r] + acc2[1][r] + acc2[2][r] + acc2[3][r];
#pragma unroll
        for (int off = 1; off < 16; off <<= 1) s += __shfl_xor(s, off, 64);
        mu[r] = s * (1.0f / 64.0f);
        float d0 = acc2[0][r] - mu[r], d1 = acc2[1][r] - mu[r];
        float d2 = acc2[2][r] - mu[r], d3 = acc2[3][r] - mu[r];
        float vv = d0 * d0 + d1 * d1 + d2 * d2 + d3 * d3;
#pragma unroll
        for (int off = 1; off < 16; off <<= 1) vv += __shfl_xor(vv, off, 64);
        inv[r] = rsqrtf(vv * (1.0f / 64.0f) + LN_EPS);
    }

    // ---- store bf16 (+ stash for gate) ----
#pragma unroll
    for (int c = 0; c < 4; c++)
#pragma unroll
        for (int r = 0; r < 4; r++) {
            int node = base + q * 4 + r;
            float o = (acc2[c][r] - mu[r]) * inv[r] * lgv[c] + lbv[c];
            unsigned short ob = f2bf(o);
            if (node < NN) xout[((size_t)node << 6) + c * 16 + n] = ob;
            if (LAST) aw[(q * 4 + r) * 64 + c * 16 + n] = ob;
        }

    // ---- fused gate MLP (last layer) ----
    if (LAST) {
        short8 B3f[2][2];
#pragma unroll
        for (int ks = 0; ks < 2; ks++)
#pragma unroll
            for (int c = 0; c < 2; c++) {
                short8 f;
#pragma unroll
                for (int j = 0; j < 8; j++) {
                    int k = ks * 32 + q * 8 + j;
                    f[j] = (short)f2bf(gw1[k * 32 + c * 16 + n]);
                }
                B3f[ks][c] = f;
            }
        const short8* gp = (const short8*)(aw + n * 64);
        short8 G0 = gp[q];
        short8 G1 = gp[4 + q];
        floatx4 acc3[2];
#pragma unroll
        for (int c = 0; c < 2; c++) {
            float bv = gb1[c * 16 + n];
            floatx4 a = {bv, bv, bv, bv};
            a = __builtin_amdgcn_mfma_f32_16x16x32_bf16(G0, B3f[0][c], a, 0, 0, 0);
            a = __builtin_amdgcn_mfma_f32_16x16x32_bf16(G1, B3f[1][c], a, 0, 0, 0);
            acc3[c] = a;
        }
        float gw2v0 = gw2[n], gw2v1 = gw2[16 + n];
        float gb2v = gb2[0];
#pragma unroll
        for (int r = 0; r < 4; r++) {
            float v0 = acc3[0][r];
            v0 = v0 / (1.0f + __expf(-v0));
            float v1 = acc3[1][r];
            v1 = v1 / (1.0f + __expf(-v1));
            float gsum = v0 * gw2v0 + v1 * gw2v1;
#pragma unroll
            for (int off = 1; off < 16; off <<= 1) gsum += __shfl_xor(gsum, off, 64);
            int node = base + q * 4 + r;
            if (n == 0 && node < NN) gate[node] = gsum + gb2v;
        }
    }
}

// ================= per-graph softmax pooling (4 waves per graph, bf16 feats) =================
__global__ __launch_bounds__(256) void k_pool(const unsigned short* __restrict__ xf,
                                              const float* __restrict__ gate,
                                              const int* __restrict__ batch,
                                              float* __restrict__ out) {
    __shared__ float redm[4];
    __shared__ float reds[4];
    __shared__ float racc[4][D];
    int g = blockIdx.x;
    int w = threadIdx.x >> 6;
    int lane = threadIdx.x & 63;

    int lo = 0, hi = NN;
    while (lo < hi) { int mid = (lo + hi) >> 1; if (batch[mid] < g) lo = mid + 1; else hi = mid; }
    int start = lo;
    hi = NN;
    while (lo < hi) { int mid = (lo + hi) >> 1; if (batch[mid] < g + 1) lo = mid + 1; else hi = mid; }
    int end = lo;

    if (start >= end) {
        if (w == 0) out[((size_t)g << 6) + lane] = 0.0f;
        return;
    }

    float m = -INFINITY;
    for (int i = start + (int)threadIdx.x; i < end; i += 256) m = fmaxf(m, gate[i]);
#pragma unroll
    for (int mm = 32; mm >= 1; mm >>= 1) m = fmaxf(m, __shfl_xor(m, mm, 64));
    if (lane == 0) redm[w] = m;
    __syncthreads();
    m = fmaxf(fmaxf(redm[0], redm[1]), fmaxf(redm[2], redm[3]));

    float s = 0.0f;
    for (int i = start + (int)threadIdx.x; i < end; i += 256) s += __expf(gate[i] - m);
#pragma unroll
    for (int mm = 32; mm >= 1; mm >>= 1) s += __shfl_xor(s, mm, 64);
    if (lane == 0) reds[w] = s;
    __syncthreads();
    s = (reds[0] + reds[1]) + (reds[2] + reds[3]);

    float acc = 0.0f;
    for (int i = start + w; i < end; i += 4)
        acc += __expf(gate[i] - m) * bfu2f(xf[((size_t)i << 6) + lane]);
    racc[w][lane] = acc;
    __syncthreads();
    if (w == 0)
        out[((size_t)g << 6) + lane] =
            ((racc[0][lane] + racc[1][lane]) + (racc[2][lane] + racc[3][lane])) / s;
}

extern "C" void kernel_launch(void* const* d_in, const int* in_sizes, int n_in,
                              void* d_out, int out_size, void* d_ws, size_t ws_size,
                              hipStream_t stream) {
    const float* x   = (const float*)d_in[0];
    const int* ei    = (const int*)d_in[1];
    const int* batch = (const int*)d_in[2];
    const float* W1  = (const float*)d_in[3];
    const float* b1  = (const float*)d_in[4];
    const float* W2  = (const float*)d_in[5];
    const float* b2  = (const float*)d_in[6];
    const float* eps = (const float*)d_in[7];
    const float* lng = (const float*)d_in[8];
    const float* lnb = (const float*)d_in[9];
    const float* gw1 = (const float*)d_in[10];
    const float* gb1 = (const float*)d_in[11];
    const float* gw2 = (const float*)d_in[12];
    const float* gb2 = (const float*)d_in[13];

    const int* src = ei;
    const int* dst = ei + NE;

    // workspace layout (~39 MB)
    unsigned short* xb = (unsigned short*)d_ws;                // NN*64 bf16 (ping)
    unsigned short* h  = xb + (size_t)NN * D;                  // NN*64 bf16 (pong)
    float* gate        = (float*)(h + (size_t)NN * D);         // NN f32
    int* row_ptr       = (int*)(gate + NN);                    // NN+1
    int* col           = row_ptr + NN + 1;                     // NE
    unsigned int* tmp  = (unsigned int*)(col + NE);            // NE
    int* btot          = (int*)(tmp + NE);                     // NB
    int* bbase         = btot + NB;                            // NB+1
    int* bcur          = bbase + NB + 1;                       // NBK*16

    float* out = (float*)d_out;

    // ---- CSR build (bucketed, no per-node global histogram) ----
    hipMemsetAsync(btot, 0, (size_t)NB * sizeof(int), stream);
    k_conv<<<(NN * D) / 256, 256, 0, stream>>>(x, xb);
    k_bcount<<<NE / EPB, 256, 0, stream>>>(dst, btot);
    k_bscan<<<1, 512, 0, stream>>>(btot, bbase);
    k_bcurinit<<<1, 512, 0, stream>>>(bbase, bcur, row_ptr);
    k_part<<<NE / EPB, 256, 0, stream>>>(src, dst, bcur, tmp);
    k_bfill<<<NBK, 256, 0, stream>>>(tmp, bbase, row_ptr, col);

    // ---- 3 GIN layers: gather (bf16->bf16 h) then MFMA MLP ----
    k_gather<<<NN / 16, 256, 0, stream>>>(xb, h, row_ptr, col, eps + 0);
    k_mfma<0><<<NTILE, 256, 0, stream>>>(h, xb,
        W1 + 0 * D * D, b1 + 0 * D, W2 + 0 * D * D, b2 + 0 * D,
        lng + 0 * D, lnb + 0 * D, gw1, gb1, gw2, gb2, gate);

    k_gather<<<NN / 16, 256, 0, stream>>>(xb, h, row_ptr, col, eps + 1);
    k_mfma<0><<<NTILE, 256, 0, stream>>>(h, xb,
        W1 + 1 * D * D, b1 + 1 * D, W2 + 1 * D * D, b2 + 1 * D,
        lng + 1 * D, lnb + 1 * D, gw1, gb1, gw2, gb2, gate);

    k_gather<<<NN / 16, 256, 0, stream>>>(xb, h, row_ptr, col, eps + 2);
    k_mfma<1><<<NTILE, 256, 0, stream>>>(h, xb,
        W1 + 2 * D * D, b1 + 2 * D, W2 + 2 * D * D, b2 + 2 * D,
        lng + 2 * D, lnb + 2 * D, gw1, gb1, gw2, gb2, gate);

    k_pool<<<NG, 256, 0, stream>>>(xb, gate, batch, out);
}